// Round 6
// baseline (731.165 us; speedup 1.0000x reference)
//
#include <hip/hip_runtime.h>
#include <cstdint>
#include <cstddef>

#define TOK     8192
#define DIMD    1024
#define INTERD  1024
#define NEXP    16
#define SINTER  2048
#define CAP256  36864   // 32768 + 16*256 padding capacity
#define MAXT    144     // sum ceil(cnt_e/256) <= 128 + 16
#define HBLK    32

typedef __bf16 bf16_t;
typedef __bf16 bf16x8_t __attribute__((ext_vector_type(8)));
typedef __bf16 bf16x4_t __attribute__((ext_vector_type(4)));
typedef float  f32x4_t  __attribute__((ext_vector_type(4)));

// async global->LDS, 16B per lane; LDS dest is wave-uniform base + lane*16
__device__ __forceinline__ void gload_lds16(const bf16_t* g, bf16_t* l) {
  __builtin_amdgcn_global_load_lds((const __attribute__((address_space(1))) void*)g,
                                   (__attribute__((address_space(3))) void*)l,
                                   16, 0, 0);
}

template <int N> __device__ __forceinline__ void vmwait() {
  if constexpr (N == 0)      asm volatile("s_waitcnt vmcnt(0)" ::: "memory");
  else if constexpr (N == 3) asm volatile("s_waitcnt vmcnt(3)" ::: "memory");
  else if constexpr (N == 4) asm volatile("s_waitcnt vmcnt(4)" ::: "memory");
  else if constexpr (N == 6) asm volatile("s_waitcnt vmcnt(6)" ::: "memory");
  else if constexpr (N == 8) asm volatile("s_waitcnt vmcnt(8)" ::: "memory");
}

#define SBAR __builtin_amdgcn_sched_barrier(0)

// ---------------- init ----------------
__global__ void init_kernel(int* toklist, float* wtlist, int* tile_e, int* tile_rs) {
  int i = blockIdx.x * blockDim.x + threadIdx.x;
  if (i < CAP256) { toklist[i] = -1; wtlist[i] = 0.0f; }
  if (i < 512)    { tile_e[i] = -1; tile_rs[i] = 0; }
}

// ---------------- fp32 -> bf16 plain ----------------
__global__ void cvt_kernel(const float* __restrict__ in, bf16_t* __restrict__ out, int n4) {
  int stride = gridDim.x * blockDim.x;
  for (int i = blockIdx.x * blockDim.x + threadIdx.x; i < n4; i += stride) {
    float4 v = ((const float4*)in)[i];
    bf16x4_t o;
    o[0] = (bf16_t)v.x; o[1] = (bf16_t)v.y; o[2] = (bf16_t)v.z; o[3] = (bf16_t)v.w;
    ((bf16x4_t*)out)[i] = o;
  }
}

// ---------------- fp32 -> bf16 with 16-row W1/W3 interleave ----------------
__global__ void cvt_ileave(const float* __restrict__ s1, const float* __restrict__ s3,
                           bf16_t* __restrict__ dst, int total4, int esh) {
  int stride = gridDim.x * blockDim.x;
  int fmask = (1 << esh) - 1;
  for (int i = blockIdx.x * blockDim.x + threadIdx.x; i < total4; i += stride) {
    int k4 = i & 255;            // K=1024 -> K/4=256
    int fr = i >> 8;
    int e  = fr >> esh;
    int f  = fr & fmask;
    int p  = f >> 4, s = f & 15;
    int real = ((p >> 1) << 4) + s;
    size_t srow = ((size_t)e << (esh - 1)) + real;
    const float* src = ((p & 1) ? s3 : s1) + (srow << 10) + (k4 << 2);
    float4 v = *(const float4*)src;
    bf16x4_t o;
    o[0] = (bf16_t)v.x; o[1] = (bf16_t)v.y; o[2] = (bf16_t)v.z; o[3] = (bf16_t)v.w;
    ((bf16x4_t*)dst)[i] = o;
  }
}

// ---------------- gate: softmax -> top4 (one wave/token, no atomics) ----------------
__global__ __launch_bounds__(256)
void gate_kernel(const float* __restrict__ x, const float* __restrict__ gw,
                 int* __restrict__ tkidx, float* __restrict__ tkwt) {
  int wv = threadIdx.x >> 6, lane = threadIdx.x & 63;
  int t = blockIdx.x * 4 + wv;
  const float4* xp = (const float4*)(x + (size_t)t * DIMD + lane * 16);
  float4 xv[4];
#pragma unroll
  for (int i = 0; i < 4; ++i) xv[i] = xp[i];
  float sc[NEXP];
#pragma unroll
  for (int e = 0; e < NEXP; ++e) {
    const float4* wp = (const float4*)(gw + (size_t)e * DIMD + lane * 16);
    float s = 0.0f;
#pragma unroll
    for (int i = 0; i < 4; ++i) {
      float4 w = wp[i];
      s += xv[i].x * w.x + xv[i].y * w.y + xv[i].z * w.z + xv[i].w * w.w;
    }
    sc[e] = s;
  }
#pragma unroll
  for (int off = 32; off > 0; off >>= 1)
#pragma unroll
    for (int e = 0; e < NEXP; ++e)
      sc[e] += __shfl_xor(sc[e], off, 64);
  if (lane == 0) {
    float m = sc[0];
#pragma unroll
    for (int e = 1; e < NEXP; ++e) m = fmaxf(m, sc[e]);
    float p[NEXP], s = 0.0f;
#pragma unroll
    for (int e = 0; e < NEXP; ++e) { p[e] = __expf(sc[e] - m); s += p[e]; }
    float inv = 1.0f / s;
    unsigned used = 0;
    for (int k = 0; k < 4; ++k) {
      int best = 0; float bv = -1.0f;
#pragma unroll
      for (int e = 0; e < NEXP; ++e)
        if (!((used >> e) & 1u) && p[e] > bv) { bv = p[e]; best = e; }
      used |= 1u << best;
      tkidx[t * 4 + k] = best;
      tkwt[t * 4 + k] = bv * inv;
    }
  }
}

// ---------------- per-block histogram ----------------
__global__ __launch_bounds__(256)
void hist_kernel(const int* __restrict__ tkidx, int* __restrict__ blkhist) {
  __shared__ int h[NEXP];
  if (threadIdx.x < NEXP) h[threadIdx.x] = 0;
  __syncthreads();
  int4 v = ((const int4*)tkidx)[blockIdx.x * 256 + threadIdx.x];
  atomicAdd(&h[v.x], 1);
  atomicAdd(&h[v.y], 1);
  atomicAdd(&h[v.z], 1);
  atomicAdd(&h[v.w], 1);
  __syncthreads();
  if (threadIdx.x < NEXP) blkhist[blockIdx.x * NEXP + threadIdx.x] = h[threadIdx.x];
}

// ---------------- offsets + 256-granular tile table + scatter bases ----------------
__global__ void offs_kernel(const int* __restrict__ blkhist, int* __restrict__ offsets,
                            int* __restrict__ blkbase,
                            int* __restrict__ tile_e, int* __restrict__ tile_rs) {
  if (threadIdx.x != 0 || blockIdx.x != 0) return;
  int counts[NEXP];
  for (int e = 0; e < NEXP; ++e) {
    int s = 0;
    for (int b = 0; b < HBLK; ++b) s += blkhist[b * NEXP + e];
    counts[e] = s;
  }
  int off = 0, nt = 0;
  for (int e = 0; e < NEXP; ++e) {
    offsets[e] = off;
    int c = counts[e];
    int ntile = (c + 255) >> 8;
    for (int i = 0; i < ntile; ++i) { tile_e[nt] = e; tile_rs[nt] = off + (i << 8); ++nt; }
    off += ntile << 8;
  }
  offsets[NEXP] = off;
  for (int e = 0; e < NEXP; ++e) {
    int base = offsets[e];
    for (int b = 0; b < HBLK; ++b) {
      blkbase[b * NEXP + e] = base;
      base += blkhist[b * NEXP + e];
    }
  }
}

// ---------------- scatter (LDS cursors) + record per-token slot positions ----------------
__global__ __launch_bounds__(256)
void scat_kernel(const int* __restrict__ tkidx, const float* __restrict__ tkwt,
                 const int* __restrict__ blkbase,
                 int* __restrict__ toklist, float* __restrict__ wtlist,
                 int4* __restrict__ pos4) {
  __shared__ int cur[NEXP];
  if (threadIdx.x < NEXP) cur[threadIdx.x] = blkbase[blockIdx.x * NEXP + threadIdx.x];
  __syncthreads();
  int idx = blockIdx.x * 256 + threadIdx.x;
  int4 v = ((const int4*)tkidx)[idx];
  float4 w = ((const float4*)tkwt)[idx];
  int p0 = atomicAdd(&cur[v.x], 1); toklist[p0] = idx; wtlist[p0] = w.x;
  int p1 = atomicAdd(&cur[v.y], 1); toklist[p1] = idx; wtlist[p1] = w.y;
  int p2 = atomicAdd(&cur[v.z], 1); toklist[p2] = idx; wtlist[p2] = w.z;
  int p3 = atomicAdd(&cur[v.w], 1); toklist[p3] = idx; wtlist[p3] = w.w;
  pos4[idx] = make_int4(p0, p1, p2, p3);
}

// ---------------- fuse: out[t] += sum of 4 routed contribution rows ----------------
__global__ __launch_bounds__(256)
void fuse_kernel(const int4* __restrict__ pos4, const bf16_t* __restrict__ Yg,
                 float* __restrict__ out) {
  int t = blockIdx.x;
  int4 p = pos4[t];
  int c = threadIdx.x;   // 256 threads x float4 = 1024 cols
  float4 o = ((const float4*)(out + (size_t)t * DIMD))[c];
  bf16x4_t y0 = ((const bf16x4_t*)(Yg + (size_t)p.x * DIMD))[c];
  bf16x4_t y1 = ((const bf16x4_t*)(Yg + (size_t)p.y * DIMD))[c];
  bf16x4_t y2 = ((const bf16x4_t*)(Yg + (size_t)p.z * DIMD))[c];
  bf16x4_t y3 = ((const bf16x4_t*)(Yg + (size_t)p.w * DIMD))[c];
  o.x += (float)y0[0] + (float)y1[0] + (float)y2[0] + (float)y3[0];
  o.y += (float)y0[1] + (float)y1[1] + (float)y2[1] + (float)y3[1];
  o.z += (float)y0[2] + (float)y1[2] + (float)y2[2] + (float)y3[2];
  o.w += (float)y0[3] + (float)y1[3] + (float)y2[3] + (float)y3[3];
  ((float4*)(out + (size_t)t * DIMD))[c] = o;
}

// ============ BK=32, 4-buffer deep-prefetch GEMM (1 barrier + 1 vmcnt per K-tile) ============
// LDS per buffer (k-major, conflict-free, no swizzle):
//   A region: [kslot 0..3][BM rows][16B]   (BM*64 bytes)
//   B region: [kslot 0..3][256 rows][16B]  (16384 bytes)
// Tile t lives in buf[t&3]; tile t+3 staged during tile t (issued right after the
// publish barrier, so the previous tenant's readers are provably done).
// EPI: 0 = dual silu epilogue -> H bf16 (B is 16-row interleaved [W1;W3])
//      1 = plain bf16 store of weighted contribution (+wt*b2) into Yg
//      2 = dense fp32 write out (+b2)
template <int BM, bool TABLE, int EPI>
__global__ __launch_bounds__(512, 2)
void gemm4b(const bf16_t* __restrict__ Ag, const bf16_t* __restrict__ Bw,
            const float* __restrict__ bias1, const float* __restrict__ bias3,
            void* __restrict__ Outp,
            const int* __restrict__ tile_e, const int* __restrict__ tile_rs,
            const int* __restrict__ toklist, const float* __restrict__ wtlist,
            int K, int ldOut, size_t strideB, int biasStride) {
  constexpr int BN = 256;
  constexpr int MI = BM / 32;               // A frags per wave
  constexpr int NG = MI / 4;                // MFMA groups per tile
  constexpr int RB = (BM == 256) ? 8 : 7;
  constexpr int AJ = BM / 128;              // A staging loads per tile
  constexpr int ABY = BM * 64;              // A region bytes
  constexpr int BUFBY = ABY + 16384;        // bytes per buffer
  constexpr int LPT = AJ + 2;               // staging loads per tile
  __shared__ __align__(16) bf16_t lds[4 * BUFBY / 2];

  int rowstart, e = 0;
  if constexpr (TABLE) {
    e = tile_e[blockIdx.y];
    if (e < 0) return;
    rowstart = tile_rs[blockIdx.y];
  } else {
    rowstart = blockIdx.y * BM;
  }
  const bf16_t* Bwp = Bw + (TABLE ? (size_t)e * strideB : (size_t)0);
  const int boff = TABLE ? e * biasStride : 0;

  const int tid = threadIdx.x, lane = tid & 63, wv = tid >> 6;
  const int wm = wv >> 2, wn = wv & 3;

  // ---- staging source pointers (linear; k-major LDS needs no swizzle) ----
  int rA = tid & ((1 << RB) - 1);
  int ksA = tid >> RB;
  long arow;
  if constexpr (TABLE && EPI == 0) {
    int t = toklist[rowstart + rA];
    arow = (t < 0) ? 0 : t;
  } else {
    arow = rowstart + rA;
  }
  const bf16_t* srcA = Ag + (size_t)arow * K + ksA * 8;
  int rBr = tid & 255, ksB = tid >> 8;
  const bf16_t* srcB = Bwp + (size_t)((int)blockIdx.x * BN + rBr) * K + ksB * 8;

#define STAGE(KT)                                                               \
  do {                                                                          \
    bf16_t* db_ = (bf16_t*)lds + ((KT) & 3) * (BUFBY / 2);                      \
    _Pragma("unroll")                                                           \
    for (int j_ = 0; j_ < AJ; ++j_)                                             \
      gload_lds16(srcA + (KT) * 32 + j_ * ((512 >> RB) * 8),                    \
                  db_ + j_ * 4096 + tid * 8);                                   \
    _Pragma("unroll")                                                           \
    for (int j_ = 0; j_ < 2; ++j_)                                              \
      gload_lds16(srcB + (KT) * 32 + j_ * 16,                                   \
                  db_ + ABY / 2 + j_ * 4096 + tid * 8);                         \
  } while (0)

  f32x4_t acc[MI][4] = {};

  // one K-tile: vmcnt -> barrier (publish) -> stage t+3 -> reads+MFMA groups
#define TILE(VMN, DOSTG)                                                        \
  do {                                                                          \
    vmwait<VMN>(); SBAR;                                                        \
    __builtin_amdgcn_s_barrier(); SBAR;                                         \
    if (DOSTG) STAGE(kt + 3);                                                   \
    const char* bufb = (const char*)lds + (kt & 3) * BUFBY;                     \
    bf16x8_t bfr[4];                                                            \
    _Pragma("unroll")                                                           \
    for (int ni = 0; ni < 4; ++ni) {                                            \
      int ct = wn * 64 + ni * 16 + (lane & 15);                                 \
      bfr[ni] = *(const bf16x8_t*)(bufb + ABY + (lane >> 4) * 4096 + ct * 16);  \
    }                                                                           \
    _Pragma("unroll")                                                           \
    for (int g = 0; g < NG; ++g) {                                              \
      bf16x8_t afr[4];                                                          \
      _Pragma("unroll")                                                         \
      for (int q = 0; q < 4; ++q) {                                             \
        int row = wm * (BM / 2) + (g * 4 + q) * 16 + (lane & 15);               \
        afr[q] = *(const bf16x8_t*)(bufb + (lane >> 4) * (BM * 16) + row * 16); \
      }                                                                         \
      asm volatile("s_waitcnt lgkmcnt(0)" ::: "memory"); SBAR;                  \
      __builtin_amdgcn_s_setprio(1);                                            \
      _Pragma("unroll")                                                         \
      for (int q = 0; q < 4; ++q)                                               \
        _Pragma("unroll")                                                       \
        for (int ni = 0; ni < 4; ++ni)                                          \
          acc[g * 4 + q][ni] = __builtin_amdgcn_mfma_f32_16x16x32_bf16(         \
              afr[q], bfr[ni], acc[g * 4 + q][ni], 0, 0, 0);                    \
      __builtin_amdgcn_s_setprio(0); SBAR;                                      \
    }                                                                           \
  } while (0)

  const int NTK = K >> 5;

  // prologue: stage tiles 0,1,2 (3*LPT loads in flight)
  STAGE(0); STAGE(1); STAGE(2);

  int kt = 0;
  for (; kt < NTK - 2; ++kt) {
    TILE(2 * LPT, kt + 3 < NTK);
  }
  TILE(LPT, false); ++kt;
  TILE(0, false);

  // ---------------- epilogue ----------------
  if constexpr (EPI == 0) {
    float b1v[2], b3v[2];
    int rcbase = (int)blockIdx.x * 128 + wn * 32 + (lane & 15);
#pragma unroll
    for (int ni2 = 0; ni2 < 2; ++ni2) {
      b1v[ni2] = bias1[boff + rcbase + ni2 * 16];
      b3v[ni2] = bias3[boff + rcbase + ni2 * 16];
    }
    bf16_t* Hout = (bf16_t*)Outp;
#pragma unroll
    for (int mi = 0; mi < MI; ++mi)
#pragma unroll
      for (int rg = 0; rg < 4; ++rg) {
        int rt = wm * (BM / 2) + mi * 16 + ((lane >> 4) << 2) + rg;
        int grow = rowstart + rt;
        float wt = 1.0f;
        if constexpr (TABLE) wt = wtlist[grow];
        size_t ob = (size_t)grow * ldOut + rcbase;
#pragma unroll
        for (int ni2 = 0; ni2 < 2; ++ni2) {
          float v1 = acc[mi][2 * ni2][rg] + b1v[ni2];
          float v3 = acc[mi][2 * ni2 + 1][rg] + b3v[ni2];
          float sg = v1 / (1.0f + __expf(-v1));
          Hout[ob + ni2 * 16] = (bf16_t)(sg * v3 * wt);
        }
      }
  } else if constexpr (EPI == 1) {
    float bv[4];
    int colbase = (int)blockIdx.x * BN + wn * 64 + (lane & 15);
#pragma unroll
    for (int ni = 0; ni < 4; ++ni) bv[ni] = bias1[boff + colbase + ni * 16];
    bf16_t* Yout = (bf16_t*)Outp;
#pragma unroll
    for (int mi = 0; mi < MI; ++mi)
#pragma unroll
      for (int rg = 0; rg < 4; ++rg) {
        int rt = wm * (BM / 2) + mi * 16 + ((lane >> 4) << 2) + rg;
        int grow = rowstart + rt;
        float wt = wtlist[grow];
        size_t ob = (size_t)grow * ldOut + colbase;
#pragma unroll
        for (int ni = 0; ni < 4; ++ni)
          Yout[ob + ni * 16] = (bf16_t)(acc[mi][ni][rg] + wt * bv[ni]);
      }
  } else {
    float bv[4];
    int colbase = (int)blockIdx.x * BN + wn * 64 + (lane & 15);
#pragma unroll
    for (int ni = 0; ni < 4; ++ni) bv[ni] = bias1[boff + colbase + ni * 16];
    float* Fout = (float*)Outp;
#pragma unroll
    for (int mi = 0; mi < MI; ++mi)
#pragma unroll
      for (int rg = 0; rg < 4; ++rg) {
        int rt = wm * (BM / 2) + mi * 16 + ((lane >> 4) << 2) + rg;
        int grow = rowstart + rt;
        size_t ob = (size_t)grow * ldOut + colbase;
#pragma unroll
        for (int ni = 0; ni < 4; ++ni)
          Fout[ob + ni * 16] = acc[mi][ni][rg] + bv[ni];
      }
  }
#undef TILE
#undef STAGE
}

// ---------------- host ----------------
extern "C" void kernel_launch(void* const* d_in, const int* in_sizes, int n_in,
                              void* d_out, int out_size, void* d_ws, size_t ws_size,
                              hipStream_t stream) {
  const float* x   = (const float*)d_in[0];
  const float* gw  = (const float*)d_in[1];
  const float* ew1 = (const float*)d_in[2];
  const float* eb1 = (const float*)d_in[3];
  const float* ew2 = (const float*)d_in[4];
  const float* eb2 = (const float*)d_in[5];
  const float* ew3 = (const float*)d_in[6];
  const float* eb3 = (const float*)d_in[7];
  const float* sw1 = (const float*)d_in[8];
  const float* sb1 = (const float*)d_in[9];
  const float* sw2 = (const float*)d_in[10];
  const float* sb2 = (const float*)d_in[11];
  const float* sw3 = (const float*)d_in[12];
  const float* sb3 = (const float*)d_in[13];
  float* out = (float*)d_out;
  (void)ws_size;

  char* ws = (char*)d_ws;
  size_t off = 0;
  auto alloc = [&](size_t bytes) -> void* {
    off = (off + 255) & ~(size_t)255;
    void* p = ws + off;
    off += bytes;
    return p;
  };

  bf16_t* xb    = (bf16_t*)alloc((size_t)TOK * DIMD * 2);                  // 16 MB
  bf16_t* ew13i = (bf16_t*)alloc((size_t)NEXP * 2 * INTERD * DIMD * 2);    // 64 MB
  bf16_t* ew2b  = (bf16_t*)alloc((size_t)NEXP * DIMD * INTERD * 2);        // 32 MB
  bf16_t* sw13i = (bf16_t*)alloc((size_t)2 * SINTER * DIMD * 2);           // 16 MB
  bf16_t* sw2b  = (bf16_t*)alloc((size_t)DIMD * SINTER * 2);               // 4 MB
  // H union: shared Hs (8192x2048) / routed Hg (36864x1024), disjoint time windows
  bf16_t* Hun   = (bf16_t*)alloc((size_t)CAP256 * INTERD * 2);             // 72 MB
  bf16_t* Hs    = Hun;
  bf16_t* Hg    = Hun;
  // Yg (72 MB bf16) ALIASES xb+ew13i: both are dead once routed gemm1 completes,
  // and cvt refills them at the start of every (replayed) call.
  bf16_t* Yg    = xb;
  int*   toklist = (int*)alloc(CAP256 * 4);
  float* wtlist  = (float*)alloc(CAP256 * 4);
  int*   offsets = (int*)alloc((NEXP + 1) * 4);
  int*   blkhist = (int*)alloc(HBLK * NEXP * 4);
  int*   blkbase = (int*)alloc(HBLK * NEXP * 4);
  int*   tile_e  = (int*)alloc(512 * 4);
  int*   tile_rs = (int*)alloc(512 * 4);
  int*   tkidx   = (int*)alloc((size_t)TOK * 4 * 4);
  float* tkwt    = (float*)alloc((size_t)TOK * 4 * 4);
  int4*  pos4    = (int4*)alloc((size_t)TOK * 16);

  init_kernel<<<(CAP256 + 255) / 256, 256, 0, stream>>>(toklist, wtlist, tile_e, tile_rs);

  cvt_kernel<<<2048, 256, 0, stream>>>(x,   xb,   TOK * DIMD / 4);
  cvt_kernel<<<2048, 256, 0, stream>>>(ew2, ew2b, NEXP * DIMD * INTERD / 4);
  cvt_kernel<<<512,  256, 0, stream>>>(sw2, sw2b, DIMD * SINTER / 4);
  cvt_ileave<<<2048, 256, 0, stream>>>(ew1, ew3, ew13i, NEXP * 2 * INTERD * DIMD / 4, 11);
  cvt_ileave<<<1024, 256, 0, stream>>>(sw1, sw3, sw13i, 2 * SINTER * DIMD / 4, 12);

  gate_kernel<<<TOK / 4, 256, 0, stream>>>(x, gw, tkidx, tkwt);
  hist_kernel<<<HBLK, 256, 0, stream>>>(tkidx, blkhist);
  offs_kernel<<<1, 64, 0, stream>>>(blkhist, offsets, blkbase, tile_e, tile_rs);
  scat_kernel<<<HBLK, 256, 0, stream>>>(tkidx, tkwt, blkbase, toklist, wtlist, pos4);

  // shared expert: Hs = silu(x sw1^T + sb1)*(x sw3^T + sb3); out = Hs sw2^T + sb2
  gemm4b<256, false, 0><<<dim3(2 * SINTER / 256, TOK / 256), 512, 0, stream>>>(
      xb, sw13i, sb1, sb3, Hs, nullptr, nullptr, nullptr, nullptr,
      DIMD, SINTER, 0, 0);
  gemm4b<128, false, 2><<<dim3(DIMD / 256, TOK / 128), 512, 0, stream>>>(
      Hs, sw2b, sb2, nullptr, out, nullptr, nullptr, nullptr, nullptr,
      SINTER, DIMD, 0, 0);

  // routed experts: Hg = wt * silu(.)*(.) per 256-row tile; Yg = Hg ew2^T + wt*b2
  gemm4b<256, true, 0><<<dim3(2 * INTERD / 256, MAXT), 512, 0, stream>>>(
      xb, ew13i, eb1, eb3, Hg, tile_e, tile_rs, toklist, wtlist,
      DIMD, INTERD, (size_t)2 * INTERD * DIMD, INTERD);
  gemm4b<256, true, 1><<<dim3(DIMD / 256, MAXT), 512, 0, stream>>>(
      Hg, ew2b, eb2, nullptr, Yg, tile_e, tile_rs, toklist, wtlist,
      INTERD, DIMD, (size_t)DIMD * INTERD, DIMD);

  // combine: out[t] += sum_k Yg[pos(t,k)]
  fuse_kernel<<<TOK, 256, 0, stream>>>(pos4, Yg, out);
}

// Round 7
// 558.047 us; speedup vs baseline: 1.3102x; 1.3102x over previous
//
#include <hip/hip_runtime.h>
#include <cstdint>
#include <cstddef>

#define TOK     8192
#define DIMD    1024
#define INTERD  1024
#define NEXP    16
#define SINTER  2048
#define CAP256  36864   // 32768 + 16*256 padding capacity
#define MAXT    144     // sum ceil(cnt_e/256) <= 128 + 16
#define HBLK    32

typedef __bf16 bf16_t;
typedef __bf16 bf16x8_t __attribute__((ext_vector_type(8)));
typedef __bf16 bf16x4_t __attribute__((ext_vector_type(4)));
typedef float  f32x4_t  __attribute__((ext_vector_type(4)));

// async global->LDS, 16B per lane; LDS dest is wave-uniform base + lane*16
__device__ __forceinline__ void gload_lds16(const bf16_t* g, bf16_t* l) {
  __builtin_amdgcn_global_load_lds((const __attribute__((address_space(1))) void*)g,
                                   (__attribute__((address_space(3))) void*)l,
                                   16, 0, 0);
}

#define SBAR __builtin_amdgcn_sched_barrier(0)

// ---------------- init ----------------
__global__ void init_kernel(int* toklist, float* wtlist, int* tile_e, int* tile_rs) {
  int i = blockIdx.x * blockDim.x + threadIdx.x;
  if (i < CAP256) { toklist[i] = -1; wtlist[i] = 0.0f; }
  if (i < 512)    { tile_e[i] = -1; tile_rs[i] = 0; }
}

// ---------------- fp32 -> bf16 plain ----------------
__global__ void cvt_kernel(const float* __restrict__ in, bf16_t* __restrict__ out, int n4) {
  int stride = gridDim.x * blockDim.x;
  for (int i = blockIdx.x * blockDim.x + threadIdx.x; i < n4; i += stride) {
    float4 v = ((const float4*)in)[i];
    bf16x4_t o;
    o[0] = (bf16_t)v.x; o[1] = (bf16_t)v.y; o[2] = (bf16_t)v.z; o[3] = (bf16_t)v.w;
    ((bf16x4_t*)out)[i] = o;
  }
}

// ---------------- fp32 -> bf16 with 16-row W1/W3 interleave ----------------
__global__ void cvt_ileave(const float* __restrict__ s1, const float* __restrict__ s3,
                           bf16_t* __restrict__ dst, int total4, int esh) {
  int stride = gridDim.x * blockDim.x;
  int fmask = (1 << esh) - 1;
  for (int i = blockIdx.x * blockDim.x + threadIdx.x; i < total4; i += stride) {
    int k4 = i & 255;            // K=1024 -> K/4=256
    int fr = i >> 8;
    int e  = fr >> esh;
    int f  = fr & fmask;
    int p  = f >> 4, s = f & 15;
    int real = ((p >> 1) << 4) + s;
    size_t srow = ((size_t)e << (esh - 1)) + real;
    const float* src = ((p & 1) ? s3 : s1) + (srow << 10) + (k4 << 2);
    float4 v = *(const float4*)src;
    bf16x4_t o;
    o[0] = (bf16_t)v.x; o[1] = (bf16_t)v.y; o[2] = (bf16_t)v.z; o[3] = (bf16_t)v.w;
    ((bf16x4_t*)dst)[i] = o;
  }
}

// ---------------- gate: softmax -> top4 (one wave/token, no atomics) ----------------
__global__ __launch_bounds__(256)
void gate_kernel(const float* __restrict__ x, const float* __restrict__ gw,
                 int* __restrict__ tkidx, float* __restrict__ tkwt) {
  int wv = threadIdx.x >> 6, lane = threadIdx.x & 63;
  int t = blockIdx.x * 4 + wv;
  const float4* xp = (const float4*)(x + (size_t)t * DIMD + lane * 16);
  float4 xv[4];
#pragma unroll
  for (int i = 0; i < 4; ++i) xv[i] = xp[i];
  float sc[NEXP];
#pragma unroll
  for (int e = 0; e < NEXP; ++e) {
    const float4* wp = (const float4*)(gw + (size_t)e * DIMD + lane * 16);
    float s = 0.0f;
#pragma unroll
    for (int i = 0; i < 4; ++i) {
      float4 w = wp[i];
      s += xv[i].x * w.x + xv[i].y * w.y + xv[i].z * w.z + xv[i].w * w.w;
    }
    sc[e] = s;
  }
#pragma unroll
  for (int off = 32; off > 0; off >>= 1)
#pragma unroll
    for (int e = 0; e < NEXP; ++e)
      sc[e] += __shfl_xor(sc[e], off, 64);
  if (lane == 0) {
    float m = sc[0];
#pragma unroll
    for (int e = 1; e < NEXP; ++e) m = fmaxf(m, sc[e]);
    float p[NEXP], s = 0.0f;
#pragma unroll
    for (int e = 0; e < NEXP; ++e) { p[e] = __expf(sc[e] - m); s += p[e]; }
    float inv = 1.0f / s;
    unsigned used = 0;
    for (int k = 0; k < 4; ++k) {
      int best = 0; float bv = -1.0f;
#pragma unroll
      for (int e = 0; e < NEXP; ++e)
        if (!((used >> e) & 1u) && p[e] > bv) { bv = p[e]; best = e; }
      used |= 1u << best;
      tkidx[t * 4 + k] = best;
      tkwt[t * 4 + k] = bv * inv;
    }
  }
}

// ---------------- per-block histogram ----------------
__global__ __launch_bounds__(256)
void hist_kernel(const int* __restrict__ tkidx, int* __restrict__ blkhist) {
  __shared__ int h[NEXP];
  if (threadIdx.x < NEXP) h[threadIdx.x] = 0;
  __syncthreads();
  int4 v = ((const int4*)tkidx)[blockIdx.x * 256 + threadIdx.x];
  atomicAdd(&h[v.x], 1);
  atomicAdd(&h[v.y], 1);
  atomicAdd(&h[v.z], 1);
  atomicAdd(&h[v.w], 1);
  __syncthreads();
  if (threadIdx.x < NEXP) blkhist[blockIdx.x * NEXP + threadIdx.x] = h[threadIdx.x];
}

// ---------------- offsets + 256-granular tile table + scatter bases ----------------
__global__ void offs_kernel(const int* __restrict__ blkhist, int* __restrict__ offsets,
                            int* __restrict__ blkbase,
                            int* __restrict__ tile_e, int* __restrict__ tile_rs) {
  if (threadIdx.x != 0 || blockIdx.x != 0) return;
  int counts[NEXP];
  for (int e = 0; e < NEXP; ++e) {
    int s = 0;
    for (int b = 0; b < HBLK; ++b) s += blkhist[b * NEXP + e];
    counts[e] = s;
  }
  int off = 0, nt = 0;
  for (int e = 0; e < NEXP; ++e) {
    offsets[e] = off;
    int c = counts[e];
    int ntile = (c + 255) >> 8;
    for (int i = 0; i < ntile; ++i) { tile_e[nt] = e; tile_rs[nt] = off + (i << 8); ++nt; }
    off += ntile << 8;
  }
  offsets[NEXP] = off;
  for (int e = 0; e < NEXP; ++e) {
    int base = offsets[e];
    for (int b = 0; b < HBLK; ++b) {
      blkbase[b * NEXP + e] = base;
      base += blkhist[b * NEXP + e];
    }
  }
}

// ---------------- scatter (LDS cursors) + record per-token slot positions ----------------
__global__ __launch_bounds__(256)
void scat_kernel(const int* __restrict__ tkidx, const float* __restrict__ tkwt,
                 const int* __restrict__ blkbase,
                 int* __restrict__ toklist, float* __restrict__ wtlist,
                 int4* __restrict__ pos4) {
  __shared__ int cur[NEXP];
  if (threadIdx.x < NEXP) cur[threadIdx.x] = blkbase[blockIdx.x * NEXP + threadIdx.x];
  __syncthreads();
  int idx = blockIdx.x * 256 + threadIdx.x;
  int4 v = ((const int4*)tkidx)[idx];
  float4 w = ((const float4*)tkwt)[idx];
  int p0 = atomicAdd(&cur[v.x], 1); toklist[p0] = idx; wtlist[p0] = w.x;
  int p1 = atomicAdd(&cur[v.y], 1); toklist[p1] = idx; wtlist[p1] = w.y;
  int p2 = atomicAdd(&cur[v.z], 1); toklist[p2] = idx; wtlist[p2] = w.z;
  int p3 = atomicAdd(&cur[v.w], 1); toklist[p3] = idx; wtlist[p3] = w.w;
  pos4[idx] = make_int4(p0, p1, p2, p3);
}

// ---------------- fuse: out[t] += sum of 4 routed contribution rows ----------------
__global__ __launch_bounds__(256)
void fuse_kernel(const int4* __restrict__ pos4, const bf16_t* __restrict__ Yg,
                 float* __restrict__ out) {
  int t = blockIdx.x;
  int4 p = pos4[t];
  int c = threadIdx.x;   // 256 threads x float4 = 1024 cols
  float4 o = ((const float4*)(out + (size_t)t * DIMD))[c];
  bf16x4_t y0 = ((const bf16x4_t*)(Yg + (size_t)p.x * DIMD))[c];
  bf16x4_t y1 = ((const bf16x4_t*)(Yg + (size_t)p.y * DIMD))[c];
  bf16x4_t y2 = ((const bf16x4_t*)(Yg + (size_t)p.z * DIMD))[c];
  bf16x4_t y3 = ((const bf16x4_t*)(Yg + (size_t)p.w * DIMD))[c];
  o.x += (float)y0[0] + (float)y1[0] + (float)y2[0] + (float)y3[0];
  o.y += (float)y0[1] + (float)y1[1] + (float)y2[1] + (float)y3[1];
  o.z += (float)y0[2] + (float)y1[2] + (float)y2[2] + (float)y3[2];
  o.w += (float)y0[3] + (float)y1[3] + (float)y2[3] + (float)y3[3];
  ((float4*)(out + (size_t)t * DIMD))[c] = o;
}

// ============ BMx256 GEMM, BK=64, round-5 4-phase counted-vmcnt schedule ============
// BM=256: 4 phases/K-tile (ks,MH); stage {Ah0,Bh0,Bh1}@ph0 (vmcnt(6) drains prev Ah1),
//         {Ah1}@ph1, vmcnt(2)@ph3. BM=128: 2 phases/K-tile, full stage @ph0, vmcnt(0)@ph1.
// Every wait precedes a barrier; ds_reads of a phase follow the publishing barrier.
// EPI: 0 = dual silu epilogue -> H bf16 (B is 16-row interleaved [W1;W3])
//      1 = plain bf16 store of weighted contribution (+wt*b2) into Yg
//      2 = dense fp32 write out (+b2)
template <int BM, bool TABLE, int EPI>
__global__ __launch_bounds__(512, 2)
void gemm8p(const bf16_t* __restrict__ Ag, const bf16_t* __restrict__ Bw,
            const float* __restrict__ bias1, const float* __restrict__ bias3,
            void* __restrict__ Outp,
            const int* __restrict__ tile_e, const int* __restrict__ tile_rs,
            const int* __restrict__ toklist, const float* __restrict__ wtlist,
            int K, int ldOut, size_t strideB, int biasStride) {
  constexpr int BN = 256;
  constexpr int AH = BM / 128;          // A half-tiles (1 or 2)
  constexpr int MI = BM / 32;           // acc rows per wave (4 or 8)
  constexpr int ABYTES = BM * 128;      // A region bytes per buffer
  constexpr int BUFB = ABYTES + 32768;  // bytes per buffer
  __shared__ __align__(16) bf16_t lds[BUFB];  // 2 buffers * BUFB bytes

  int rowstart, e = 0;
  if constexpr (TABLE) {
    e = tile_e[blockIdx.y];
    if (e < 0) return;
    rowstart = tile_rs[blockIdx.y];
  } else {
    rowstart = blockIdx.y * BM;
  }
  const bf16_t* Bwp = Bw + (TABLE ? (size_t)e * strideB : (size_t)0);
  const int boff = TABLE ? e * biasStride : 0;

  const int tid = threadIdx.x, lane = tid & 63, wv = tid >> 6;
  const int wm = wv >> 2, wn = wv & 3;
  const int xsw = (lane & 7) << 4;          // XOR swizzle (byte bits 4-6)
  const int klo = (lane >> 4) * 16;         // k-byte offset within MFMA step

  // ---- staging source pointers (pre-swizzled global: slot = (idx&7) ^ (row&7)) ----
  const bf16_t* srcpA[4];
  const bf16_t* srcpB[4];
#pragma unroll
  for (int h = 0; h < AH; ++h)
#pragma unroll
    for (int j = 0; j < 2; ++j) {
      int idx = tid + j * 512;
      int r = h * 128 + (idx >> 3);
      int slot = (idx & 7) ^ ((idx >> 3) & 7);
      long arow;
      if constexpr (TABLE && EPI == 0) {
        int t = toklist[rowstart + r];
        arow = (t < 0) ? 0 : t;
      } else {
        arow = rowstart + r;
      }
      srcpA[h * 2 + j] = Ag + (size_t)arow * K + slot * 8;
    }
#pragma unroll
  for (int h = 0; h < 2; ++h)
#pragma unroll
    for (int j = 0; j < 2; ++j) {
      int idx = tid + j * 512;
      int r = h * 128 + (idx >> 3);
      int slot = (idx & 7) ^ ((idx >> 3) & 7);
      srcpB[h * 2 + j] = Bwp + (size_t)((int)blockIdx.x * BN + r) * K + slot * 8;
    }

#define STG_A(H, NB, KT) do {                                                    \
    bf16_t* d_ = (bf16_t*)lds + ((NB) * BUFB + (H) * 16384) / 2 + tid * 8;       \
    gload_lds16(srcpA[(H) * 2 + 0] + (KT) * 64, d_);                             \
    gload_lds16(srcpA[(H) * 2 + 1] + (KT) * 64, d_ + 4096);                      \
  } while (0)
#define STG_B(H, NB, KT) do {                                                    \
    bf16_t* d_ = (bf16_t*)lds + ((NB) * BUFB + ABYTES + (H) * 16384) / 2 + tid * 8; \
    gload_lds16(srcpB[(H) * 2 + 0] + (KT) * 64, d_);                             \
    gload_lds16(srcpB[(H) * 2 + 1] + (KT) * 64, d_ + 4096);                      \
  } while (0)

  f32x4_t acc[MI][4] = {};
  bf16x8_t bfr[4];

  // PHASE(KS, MH, STG, WT): STG 0=none 1={Ah0,Bh0,Bh1} 2={Ah1};
  // WT 0=none 1=vmcnt(6) 2=vmcnt(2) 3=vmcnt(0)
#define PHASE(KS, MH, STG, WT, BUFP, NB, KT1) do {                               \
    bf16x8_t afr[4];                                                             \
    _Pragma("unroll")                                                            \
    for (int q = 0; q < 4; ++q) {                                                \
      int rl = wm * 64 + q * 16 + (lane & 15);                                   \
      afr[q] = *(const bf16x8_t*)((BUFP) + (MH) * 16384 +                        \
                 ((rl * 128 + (KS) * 64 + klo) ^ xsw));                          \
    }                                                                            \
    if ((MH) == 0) {                                                             \
      _Pragma("unroll")                                                          \
      for (int ni = 0; ni < 4; ++ni) {                                           \
        int ct = wn * 64 + ni * 16 + (lane & 15);                                \
        bfr[ni] = *(const bf16x8_t*)((BUFP) + ABYTES + (ct >> 7) * 16384 +       \
                   (((ct & 127) * 128 + (KS) * 64 + klo) ^ xsw));                \
      }                                                                          \
    }                                                                            \
    if ((STG) == 1) { STG_A(0, NB, KT1); STG_B(0, NB, KT1); STG_B(1, NB, KT1); } \
    else if ((STG) == 2) { STG_A(1, NB, KT1); }                                  \
    SBAR;                                                                        \
    if ((WT) == 1) asm volatile("s_waitcnt vmcnt(6)" ::: "memory");              \
    else if ((WT) == 2) asm volatile("s_waitcnt vmcnt(2)" ::: "memory");         \
    else if ((WT) == 3) asm volatile("s_waitcnt vmcnt(0)" ::: "memory");         \
    SBAR;                                                                        \
    __builtin_amdgcn_s_barrier();                                                \
    asm volatile("s_waitcnt lgkmcnt(0)" ::: "memory");                           \
    SBAR;                                                                        \
    __builtin_amdgcn_s_setprio(1);                                               \
    _Pragma("unroll")                                                            \
    for (int q = 0; q < 4; ++q)                                                  \
      _Pragma("unroll")                                                          \
      for (int ni = 0; ni < 4; ++ni)                                             \
        acc[(MH) * 4 + q][ni] = __builtin_amdgcn_mfma_f32_16x16x32_bf16(         \
            afr[q], bfr[ni], acc[(MH) * 4 + q][ni], 0, 0, 0);                    \
    __builtin_amdgcn_s_setprio(0);                                               \
    __builtin_amdgcn_s_barrier();                                                \
    SBAR;                                                                        \
  } while (0)

  const int NTK = K >> 6;

  // prologue: stage full tile 0 into buf0, drain, publish
  STG_A(0, 0, 0);
  STG_B(0, 0, 0);
  STG_B(1, 0, 0);
  if constexpr (AH == 2) STG_A(1, 0, 0);
  SBAR;
  asm volatile("s_waitcnt vmcnt(0)" ::: "memory");
  SBAR;
  __builtin_amdgcn_s_barrier();
  SBAR;

  if constexpr (BM == 256) {
    for (int kt = 0; kt < NTK - 1; ++kt) {
      const char* bufp = (const char*)lds + (kt & 1) * BUFB;
      int nb = (kt + 1) & 1, k1 = kt + 1;
      PHASE(0, 0, 1, 1, bufp, nb, k1);
      PHASE(0, 1, 2, 0, bufp, nb, k1);
      PHASE(1, 0, 0, 0, bufp, nb, k1);
      PHASE(1, 1, 0, 2, bufp, nb, k1);
    }
    const char* bufp = (const char*)lds + ((NTK - 1) & 1) * BUFB;
    PHASE(0, 0, 0, 3, bufp, 0, 0);
    PHASE(0, 1, 0, 0, bufp, 0, 0);
    PHASE(1, 0, 0, 0, bufp, 0, 0);
    PHASE(1, 1, 0, 0, bufp, 0, 0);
  } else {
    for (int kt = 0; kt < NTK; ++kt) {
      const char* bufp = (const char*)lds + (kt & 1) * BUFB;
      int nb = (kt + 1) & 1, k1 = kt + 1;
      int stg = (kt + 1 < NTK) ? 1 : 0;
      PHASE(0, 0, stg, 0, bufp, nb, k1);
      PHASE(1, 0, 0, 3, bufp, nb, k1);
    }
  }

  // ---------------- epilogue ----------------
  if constexpr (EPI == 0) {
    float b1v[2], b3v[2];
    int rcbase = (int)blockIdx.x * 128 + wn * 32 + (lane & 15);
#pragma unroll
    for (int ni2 = 0; ni2 < 2; ++ni2) {
      b1v[ni2] = bias1[boff + rcbase + ni2 * 16];
      b3v[ni2] = bias3[boff + rcbase + ni2 * 16];
    }
    bf16_t* Hout = (bf16_t*)Outp;
#pragma unroll
    for (int mi = 0; mi < MI; ++mi)
#pragma unroll
      for (int rg = 0; rg < 4; ++rg) {
        int Rb = ((mi >= 4) ? 128 : 0) + wm * 64 + (mi & 3) * 16;
        int rt = Rb + ((lane >> 4) << 2) + rg;
        int grow = rowstart + rt;
        float wt = 1.0f;
        if constexpr (TABLE) wt = wtlist[grow];
        size_t ob = (size_t)grow * ldOut + rcbase;
#pragma unroll
        for (int ni2 = 0; ni2 < 2; ++ni2) {
          float v1 = acc[mi][2 * ni2][rg] + b1v[ni2];
          float v3 = acc[mi][2 * ni2 + 1][rg] + b3v[ni2];
          float sg = v1 / (1.0f + __expf(-v1));
          Hout[ob + ni2 * 16] = (bf16_t)(sg * v3 * wt);
        }
      }
  } else if constexpr (EPI == 1) {
    float bv[4];
    int colbase = (int)blockIdx.x * BN + wn * 64 + (lane & 15);
#pragma unroll
    for (int ni = 0; ni < 4; ++ni) bv[ni] = bias1[boff + colbase + ni * 16];
    bf16_t* Yout = (bf16_t*)Outp;
#pragma unroll
    for (int mi = 0; mi < MI; ++mi)
#pragma unroll
      for (int rg = 0; rg < 4; ++rg) {
        int Rb = ((mi >= 4) ? 128 : 0) + wm * 64 + (mi & 3) * 16;
        int rt = Rb + ((lane >> 4) << 2) + rg;
        int grow = rowstart + rt;
        float wt = wtlist[grow];
        size_t ob = (size_t)grow * ldOut + colbase;
#pragma unroll
        for (int ni = 0; ni < 4; ++ni)
          Yout[ob + ni * 16] = (bf16_t)(acc[mi][ni][rg] + wt * bv[ni]);
      }
  } else {
    float bv[4];
    int colbase = (int)blockIdx.x * BN + wn * 64 + (lane & 15);
#pragma unroll
    for (int ni = 0; ni < 4; ++ni) bv[ni] = bias1[boff + colbase + ni * 16];
    float* Fout = (float*)Outp;
#pragma unroll
    for (int mi = 0; mi < MI; ++mi)
#pragma unroll
      for (int rg = 0; rg < 4; ++rg) {
        int Rb = ((mi >= 4) ? 128 : 0) + wm * 64 + (mi & 3) * 16;
        int rt = Rb + ((lane >> 4) << 2) + rg;
        int grow = rowstart + rt;
        size_t ob = (size_t)grow * ldOut + colbase;
#pragma unroll
        for (int ni = 0; ni < 4; ++ni)
          Fout[ob + ni * 16] = acc[mi][ni][rg] + bv[ni];
      }
  }
#undef PHASE
#undef STG_A
#undef STG_B
}

// ---------------- host ----------------
extern "C" void kernel_launch(void* const* d_in, const int* in_sizes, int n_in,
                              void* d_out, int out_size, void* d_ws, size_t ws_size,
                              hipStream_t stream) {
  const float* x   = (const float*)d_in[0];
  const float* gw  = (const float*)d_in[1];
  const float* ew1 = (const float*)d_in[2];
  const float* eb1 = (const float*)d_in[3];
  const float* ew2 = (const float*)d_in[4];
  const float* eb2 = (const float*)d_in[5];
  const float* ew3 = (const float*)d_in[6];
  const float* eb3 = (const float*)d_in[7];
  const float* sw1 = (const float*)d_in[8];
  const float* sb1 = (const float*)d_in[9];
  const float* sw2 = (const float*)d_in[10];
  const float* sb2 = (const float*)d_in[11];
  const float* sw3 = (const float*)d_in[12];
  const float* sb3 = (const float*)d_in[13];
  float* out = (float*)d_out;
  (void)ws_size;

  char* ws = (char*)d_ws;
  size_t off = 0;
  auto alloc = [&](size_t bytes) -> void* {
    off = (off + 255) & ~(size_t)255;
    void* p = ws + off;
    off += bytes;
    return p;
  };

  bf16_t* xb    = (bf16_t*)alloc((size_t)TOK * DIMD * 2);                  // 16 MB
  bf16_t* ew13i = (bf16_t*)alloc((size_t)NEXP * 2 * INTERD * DIMD * 2);    // 64 MB
  bf16_t* ew2b  = (bf16_t*)alloc((size_t)NEXP * DIMD * INTERD * 2);        // 32 MB
  bf16_t* sw13i = (bf16_t*)alloc((size_t)2 * SINTER * DIMD * 2);           // 16 MB
  bf16_t* sw2b  = (bf16_t*)alloc((size_t)DIMD * SINTER * 2);               // 4 MB
  // H union: shared Hs (8192x2048) / routed Hg (36864x1024), disjoint time windows
  bf16_t* Hun   = (bf16_t*)alloc((size_t)CAP256 * INTERD * 2);             // 72 MB
  bf16_t* Hs    = Hun;
  bf16_t* Hg    = Hun;
  // Yg (75.5 MB bf16) ALIASES xb+ew13i (80 MB): both dead once routed gemm1 completes;
  // cvt refills them at the start of every (replayed) call.
  bf16_t* Yg    = xb;
  int*   toklist = (int*)alloc(CAP256 * 4);
  float* wtlist  = (float*)alloc(CAP256 * 4);
  int*   offsets = (int*)alloc((NEXP + 1) * 4);
  int*   blkhist = (int*)alloc(HBLK * NEXP * 4);
  int*   blkbase = (int*)alloc(HBLK * NEXP * 4);
  int*   tile_e  = (int*)alloc(512 * 4);
  int*   tile_rs = (int*)alloc(512 * 4);
  int*   tkidx   = (int*)alloc((size_t)TOK * 4 * 4);
  float* tkwt    = (float*)alloc((size_t)TOK * 4 * 4);
  int4*  pos4    = (int4*)alloc((size_t)TOK * 16);

  init_kernel<<<(CAP256 + 255) / 256, 256, 0, stream>>>(toklist, wtlist, tile_e, tile_rs);

  cvt_kernel<<<2048, 256, 0, stream>>>(x,   xb,   TOK * DIMD / 4);
  cvt_kernel<<<2048, 256, 0, stream>>>(ew2, ew2b, NEXP * DIMD * INTERD / 4);
  cvt_kernel<<<512,  256, 0, stream>>>(sw2, sw2b, DIMD * SINTER / 4);
  cvt_ileave<<<2048, 256, 0, stream>>>(ew1, ew3, ew13i, NEXP * 2 * INTERD * DIMD / 4, 11);
  cvt_ileave<<<1024, 256, 0, stream>>>(sw1, sw3, sw13i, 2 * SINTER * DIMD / 4, 12);

  gate_kernel<<<TOK / 4, 256, 0, stream>>>(x, gw, tkidx, tkwt);
  hist_kernel<<<HBLK, 256, 0, stream>>>(tkidx, blkhist);
  offs_kernel<<<1, 64, 0, stream>>>(blkhist, offsets, blkbase, tile_e, tile_rs);
  scat_kernel<<<HBLK, 256, 0, stream>>>(tkidx, tkwt, blkbase, toklist, wtlist, pos4);

  // shared expert: Hs = silu(x sw1^T + sb1)*(x sw3^T + sb3); out = Hs sw2^T + sb2
  gemm8p<256, false, 0><<<dim3(2 * SINTER / 256, TOK / 256), 512, 0, stream>>>(
      xb, sw13i, sb1, sb3, Hs, nullptr, nullptr, nullptr, nullptr,
      DIMD, SINTER, 0, 0);
  gemm8p<128, false, 2><<<dim3(DIMD / 256, TOK / 128), 512, 0, stream>>>(
      Hs, sw2b, sb2, nullptr, out, nullptr, nullptr, nullptr, nullptr,
      SINTER, DIMD, 0, 0);

  // routed experts: Hg = wt * silu(.)*(.); Yg = Hg ew2^T + wt*b2 (plain bf16 store)
  gemm8p<256, true, 0><<<dim3(2 * INTERD / 256, MAXT), 512, 0, stream>>>(
      xb, ew13i, eb1, eb3, Hg, tile_e, tile_rs, toklist, wtlist,
      DIMD, INTERD, (size_t)2 * INTERD * DIMD, INTERD);
  gemm8p<256, true, 1><<<dim3(DIMD / 256, MAXT), 512, 0, stream>>>(
      Hg, ew2b, eb2, nullptr, Yg, tile_e, tile_rs, toklist, wtlist,
      INTERD, DIMD, (size_t)DIMD * INTERD, DIMD);

  // combine: out[t] += sum_k Yg[pos(t,k)]
  fuse_kernel<<<TOK, 256, 0, stream>>>(pos4, Yg, out);
}

// Round 9
// 548.428 us; speedup vs baseline: 1.3332x; 1.0175x over previous
//
#include <hip/hip_runtime.h>
#include <cstdint>
#include <cstddef>

#define TOK     8192
#define DIMD    1024
#define INTERD  1024
#define NEXP    16
#define SINTER  2048
#define CAP256  36864   // 32768 + 16*256 padding capacity
#define MAXT    144     // sum ceil(cnt_e/256) <= 128 + 16
#define HBLK    32

typedef __bf16 bf16_t;
typedef __bf16 bf16x8_t __attribute__((ext_vector_type(8)));
typedef __bf16 bf16x4_t __attribute__((ext_vector_type(4)));
typedef float  f32x4_t  __attribute__((ext_vector_type(4)));

// async global->LDS, 16B per lane; LDS dest is wave-uniform base + lane*16
__device__ __forceinline__ void gload_lds16(const bf16_t* g, bf16_t* l) {
  __builtin_amdgcn_global_load_lds((const __attribute__((address_space(1))) void*)g,
                                   (__attribute__((address_space(3))) void*)l,
                                   16, 0, 0);
}

#define SBAR __builtin_amdgcn_sched_barrier(0)

// ---------------- init ----------------
__global__ void init_kernel(int* toklist, float* wtlist, int* tile_e, int* tile_rs) {
  int i = blockIdx.x * blockDim.x + threadIdx.x;
  if (i < CAP256) { toklist[i] = -1; wtlist[i] = 0.0f; }
  if (i < 512)    { tile_e[i] = -1; tile_rs[i] = 0; }
}

// ---------------- fp32 -> bf16, three tensors in one launch ----------------
__global__ void cvt3_kernel(const float* __restrict__ s0, bf16_t* __restrict__ d0, int n0,
                            const float* __restrict__ s1, bf16_t* __restrict__ d1, int n1,
                            const float* __restrict__ s2, bf16_t* __restrict__ d2, int n2) {
  int total = n0 + n1 + n2;
  int stride = gridDim.x * blockDim.x;
  for (int i = blockIdx.x * blockDim.x + threadIdx.x; i < total; i += stride) {
    const float* s; bf16_t* d; int j = i;
    if (j < n0) { s = s0; d = d0; }
    else if ((j - n0) < n1) { j -= n0; s = s1; d = d1; }
    else { j -= n0 + n1; s = s2; d = d2; }
    float4 v = ((const float4*)s)[j];
    bf16x4_t o;
    o[0] = (bf16_t)v.x; o[1] = (bf16_t)v.y; o[2] = (bf16_t)v.z; o[3] = (bf16_t)v.w;
    ((bf16x4_t*)d)[j] = o;
  }
}

// ---------------- fp32 -> bf16 with 16-row W1/W3 interleave ----------------
__global__ void cvt_ileave(const float* __restrict__ s1, const float* __restrict__ s3,
                           bf16_t* __restrict__ dst, int total4, int esh) {
  int stride = gridDim.x * blockDim.x;
  int fmask = (1 << esh) - 1;
  for (int i = blockIdx.x * blockDim.x + threadIdx.x; i < total4; i += stride) {
    int k4 = i & 255;            // K=1024 -> K/4=256
    int fr = i >> 8;
    int e  = fr >> esh;
    int f  = fr & fmask;
    int p  = f >> 4, s = f & 15;
    int real = ((p >> 1) << 4) + s;
    size_t srow = ((size_t)e << (esh - 1)) + real;
    const float* src = ((p & 1) ? s3 : s1) + (srow << 10) + (k4 << 2);
    float4 v = *(const float4*)src;
    bf16x4_t o;
    o[0] = (bf16_t)v.x; o[1] = (bf16_t)v.y; o[2] = (bf16_t)v.z; o[3] = (bf16_t)v.w;
    ((bf16x4_t*)dst)[i] = o;
  }
}

// ---------------- gate: softmax -> top4 (one wave/token, no atomics) ----------------
__global__ __launch_bounds__(256)
void gate_kernel(const float* __restrict__ x, const float* __restrict__ gw,
                 int* __restrict__ tkidx, float* __restrict__ tkwt) {
  int wv = threadIdx.x >> 6, lane = threadIdx.x & 63;
  int t = blockIdx.x * 4 + wv;
  const float4* xp = (const float4*)(x + (size_t)t * DIMD + lane * 16);
  float4 xv[4];
#pragma unroll
  for (int i = 0; i < 4; ++i) xv[i] = xp[i];
  float sc[NEXP];
#pragma unroll
  for (int e = 0; e < NEXP; ++e) {
    const float4* wp = (const float4*)(gw + (size_t)e * DIMD + lane * 16);
    float s = 0.0f;
#pragma unroll
    for (int i = 0; i < 4; ++i) {
      float4 w = wp[i];
      s += xv[i].x * w.x + xv[i].y * w.y + xv[i].z * w.z + xv[i].w * w.w;
    }
    sc[e] = s;
  }
#pragma unroll
  for (int off = 32; off > 0; off >>= 1)
#pragma unroll
    for (int e = 0; e < NEXP; ++e)
      sc[e] += __shfl_xor(sc[e], off, 64);
  if (lane == 0) {
    float m = sc[0];
#pragma unroll
    for (int e = 1; e < NEXP; ++e) m = fmaxf(m, sc[e]);
    float p[NEXP], s = 0.0f;
#pragma unroll
    for (int e = 0; e < NEXP; ++e) { p[e] = __expf(sc[e] - m); s += p[e]; }
    float inv = 1.0f / s;
    unsigned used = 0;
    for (int k = 0; k < 4; ++k) {
      int best = 0; float bv = -1.0f;
#pragma unroll
      for (int e = 0; e < NEXP; ++e)
        if (!((used >> e) & 1u) && p[e] > bv) { bv = p[e]; best = e; }
      used |= 1u << best;
      tkidx[t * 4 + k] = best;
      tkwt[t * 4 + k] = bv * inv;
    }
  }
}

// ---------------- per-block histogram ----------------
__global__ __launch_bounds__(256)
void hist_kernel(const int* __restrict__ tkidx, int* __restrict__ blkhist) {
  __shared__ int h[NEXP];
  if (threadIdx.x < NEXP) h[threadIdx.x] = 0;
  __syncthreads();
  int4 v = ((const int4*)tkidx)[blockIdx.x * 256 + threadIdx.x];
  atomicAdd(&h[v.x], 1);
  atomicAdd(&h[v.y], 1);
  atomicAdd(&h[v.z], 1);
  atomicAdd(&h[v.w], 1);
  __syncthreads();
  if (threadIdx.x < NEXP) blkhist[blockIdx.x * NEXP + threadIdx.x] = h[threadIdx.x];
}

// ---------------- offsets + 256-granular tile table + scatter bases ----------------
__global__ void offs_kernel(const int* __restrict__ blkhist, int* __restrict__ offsets,
                            int* __restrict__ blkbase,
                            int* __restrict__ tile_e, int* __restrict__ tile_rs) {
  if (threadIdx.x != 0 || blockIdx.x != 0) return;
  int counts[NEXP];
  for (int e = 0; e < NEXP; ++e) {
    int s = 0;
    for (int b = 0; b < HBLK; ++b) s += blkhist[b * NEXP + e];
    counts[e] = s;
  }
  int off = 0, nt = 0;
  for (int e = 0; e < NEXP; ++e) {
    offsets[e] = off;
    int c = counts[e];
    int ntile = (c + 255) >> 8;
    for (int i = 0; i < ntile; ++i) { tile_e[nt] = e; tile_rs[nt] = off + (i << 8); ++nt; }
    off += ntile << 8;
  }
  offsets[NEXP] = off;
  for (int e = 0; e < NEXP; ++e) {
    int base = offsets[e];
    for (int b = 0; b < HBLK; ++b) {
      blkbase[b * NEXP + e] = base;
      base += blkhist[b * NEXP + e];
    }
  }
}

// ---------------- scatter (LDS cursors) + record per-token slot positions ----------------
__global__ __launch_bounds__(256)
void scat_kernel(const int* __restrict__ tkidx, const float* __restrict__ tkwt,
                 const int* __restrict__ blkbase,
                 int* __restrict__ toklist, float* __restrict__ wtlist,
                 int4* __restrict__ pos4) {
  __shared__ int cur[NEXP];
  if (threadIdx.x < NEXP) cur[threadIdx.x] = blkbase[blockIdx.x * NEXP + threadIdx.x];
  __syncthreads();
  int idx = blockIdx.x * 256 + threadIdx.x;
  int4 v = ((const int4*)tkidx)[idx];
  float4 w = ((const float4*)tkwt)[idx];
  int p0 = atomicAdd(&cur[v.x], 1); toklist[p0] = idx; wtlist[p0] = w.x;
  int p1 = atomicAdd(&cur[v.y], 1); toklist[p1] = idx; wtlist[p1] = w.y;
  int p2 = atomicAdd(&cur[v.z], 1); toklist[p2] = idx; wtlist[p2] = w.z;
  int p3 = atomicAdd(&cur[v.w], 1); toklist[p3] = idx; wtlist[p3] = w.w;
  pos4[idx] = make_int4(p0, p1, p2, p3);
}

// ---------------- fuse: out[t] += sum of 4 routed contribution rows ----------------
__global__ __launch_bounds__(256)
void fuse_kernel(const int4* __restrict__ pos4, const bf16_t* __restrict__ Yg,
                 float* __restrict__ out) {
  int t = blockIdx.x;
  int4 p = pos4[t];
  int c = threadIdx.x;   // 256 threads x float4 = 1024 cols
  float4 o = ((const float4*)(out + (size_t)t * DIMD))[c];
  bf16x4_t y0 = ((const bf16x4_t*)(Yg + (size_t)p.x * DIMD))[c];
  bf16x4_t y1 = ((const bf16x4_t*)(Yg + (size_t)p.y * DIMD))[c];
  bf16x4_t y2 = ((const bf16x4_t*)(Yg + (size_t)p.z * DIMD))[c];
  bf16x4_t y3 = ((const bf16x4_t*)(Yg + (size_t)p.w * DIMD))[c];
  o.x += (float)y0[0] + (float)y1[0] + (float)y2[0] + (float)y3[0];
  o.y += (float)y0[1] + (float)y1[1] + (float)y2[1] + (float)y3[1];
  o.z += (float)y0[2] + (float)y1[2] + (float)y2[2] + (float)y3[2];
  o.w += (float)y0[3] + (float)y1[3] + (float)y2[3] + (float)y3[3];
  ((float4*)(out + (size_t)t * DIMD))[c] = o;
}

// ============ BMx256 GEMM, BK=64, 4-phase counted-vmcnt schedule + XCD swizzle ============
// PUBLISH INVARIANT: a phase's ds_reads are issued at the TOP of the phase, so they are
// covered by the PREVIOUS wait+barrier, never the phase's own. BM=256 per K-tile:
//   ph0: read{Ah0,B} (published by prev ph3 vmcnt(2)); stage{Ah0,Bh0,Bh1}(t+1); vmcnt(6)
//        [= all 8 of tile t landed, 6 of t+1 in flight]
//   ph1: read{Ah1}   (published by ph0); stage{Ah1}(t+1)
//   ph3: vmcnt(2) publishes t+1's first 6 for next iter's ph0.
// BM=128: ph0 stage all 6 of t+1; ph1 vmcnt(0) publishes them (full drain, 2-phase).
// EPI: 0 = dual silu epilogue -> H bf16 (B is 16-row interleaved [W1;W3])
//      1 = plain bf16 store of weighted contribution (+wt*b2) into Yg
//      2 = dense fp32 write out (+b2)
template <int BM, bool TABLE, int EPI>
__global__ __launch_bounds__(512, 2)
void gemm8p(const bf16_t* __restrict__ Ag, const bf16_t* __restrict__ Bw,
            const float* __restrict__ bias1, const float* __restrict__ bias3,
            void* __restrict__ Outp,
            const int* __restrict__ tile_e, const int* __restrict__ tile_rs,
            const int* __restrict__ toklist, const float* __restrict__ wtlist,
            int K, int ldOut, size_t strideB, int biasStride) {
  constexpr int BN = 256;
  constexpr int AH = BM / 128;          // A half-tiles (1 or 2)
  constexpr int MI = BM / 32;           // acc rows per wave (4 or 8)
  constexpr int ABYTES = BM * 128;      // A region bytes per buffer
  constexpr int BUFB = ABYTES + 32768;  // bytes per buffer
  __shared__ __align__(16) bf16_t lds[BUFB];  // 2 buffers * BUFB bytes

  // ---- T1: bijective XCD-chunked swizzle (grid size is a multiple of 8) ----
  int nwg = (int)(gridDim.x * gridDim.y);
  int lin = (int)(blockIdx.y * gridDim.x + blockIdx.x);
  int sw = (lin & 7) * (nwg >> 3) + (lin >> 3);
  int bx = sw % (int)gridDim.x;
  int by = sw / (int)gridDim.x;

  int rowstart, e = 0;
  if constexpr (TABLE) {
    e = tile_e[by];
    if (e < 0) return;
    rowstart = tile_rs[by];
  } else {
    rowstart = by * BM;
  }
  const bf16_t* Bwp = Bw + (TABLE ? (size_t)e * strideB : (size_t)0);
  const int boff = TABLE ? e * biasStride : 0;

  const int tid = threadIdx.x, lane = tid & 63, wv = tid >> 6;
  const int wm = wv >> 2, wn = wv & 3;
  const int xsw = (lane & 7) << 4;          // XOR swizzle (byte bits 4-6)
  const int klo = (lane >> 4) * 16;         // k-byte offset within MFMA step

  // ---- staging source pointers (pre-swizzled global: slot = (idx&7) ^ (row&7)) ----
  const bf16_t* srcpA[4];
  const bf16_t* srcpB[4];
#pragma unroll
  for (int h = 0; h < AH; ++h)
#pragma unroll
    for (int j = 0; j < 2; ++j) {
      int idx = tid + j * 512;
      int r = h * 128 + (idx >> 3);
      int slot = (idx & 7) ^ ((idx >> 3) & 7);
      long arow;
      if constexpr (TABLE && EPI == 0) {
        int t = toklist[rowstart + r];
        arow = (t < 0) ? 0 : t;
      } else {
        arow = rowstart + r;
      }
      srcpA[h * 2 + j] = Ag + (size_t)arow * K + slot * 8;
    }
#pragma unroll
  for (int h = 0; h < 2; ++h)
#pragma unroll
    for (int j = 0; j < 2; ++j) {
      int idx = tid + j * 512;
      int r = h * 128 + (idx >> 3);
      int slot = (idx & 7) ^ ((idx >> 3) & 7);
      srcpB[h * 2 + j] = Bwp + (size_t)(bx * BN + r) * K + slot * 8;
    }

#define STG_A(H, NB, KT) do {                                                    \
    bf16_t* d_ = (bf16_t*)lds + ((NB) * BUFB + (H) * 16384) / 2 + tid * 8;       \
    gload_lds16(srcpA[(H) * 2 + 0] + (KT) * 64, d_);                             \
    gload_lds16(srcpA[(H) * 2 + 1] + (KT) * 64, d_ + 4096);                      \
  } while (0)
#define STG_B(H, NB, KT) do {                                                    \
    bf16_t* d_ = (bf16_t*)lds + ((NB) * BUFB + ABYTES + (H) * 16384) / 2 + tid * 8; \
    gload_lds16(srcpB[(H) * 2 + 0] + (KT) * 64, d_);                             \
    gload_lds16(srcpB[(H) * 2 + 1] + (KT) * 64, d_ + 4096);                      \
  } while (0)

  f32x4_t acc[MI][4] = {};
  bf16x8_t bfr[4];

  // PHASE(KS, MH, STG, WT): STG 0=none 1={Ah0,Bh0,Bh1} 2={Ah1};
  // WT 0=none 1=vmcnt(6) 2=vmcnt(2) 3=vmcnt(0)
#define PHASE(KS, MH, STG, WT, BUFP, NB, KT1) do {                               \
    bf16x8_t afr[4];                                                             \
    _Pragma("unroll")                                                            \
    for (int q = 0; q < 4; ++q) {                                                \
      int rl = wm * 64 + q * 16 + (lane & 15);                                   \
      afr[q] = *(const bf16x8_t*)((BUFP) + (MH) * 16384 +                        \
                 ((rl * 128 + (KS) * 64 + klo) ^ xsw));                          \
    }                                                                            \
    if ((MH) == 0) {                                                             \
      _Pragma("unroll")                                                          \
      for (int ni = 0; ni < 4; ++ni) {                                           \
        int ct = wn * 64 + ni * 16 + (lane & 15);                                \
        bfr[ni] = *(const bf16x8_t*)((BUFP) + ABYTES + (ct >> 7) * 16384 +       \
                   (((ct & 127) * 128 + (KS) * 64 + klo) ^ xsw));                \
      }                                                                          \
    }                                                                            \
    if ((STG) == 1) { STG_A(0, NB, KT1); STG_B(0, NB, KT1); STG_B(1, NB, KT1); } \
    else if ((STG) == 2) { STG_A(1, NB, KT1); }                                  \
    SBAR;                                                                        \
    if ((WT) == 1) asm volatile("s_waitcnt vmcnt(6)" ::: "memory");              \
    else if ((WT) == 2) asm volatile("s_waitcnt vmcnt(2)" ::: "memory");         \
    else if ((WT) == 3) asm volatile("s_waitcnt vmcnt(0)" ::: "memory");         \
    SBAR;                                                                        \
    __builtin_amdgcn_s_barrier();                                                \
    asm volatile("s_waitcnt lgkmcnt(0)" ::: "memory");                           \
    SBAR;                                                                        \
    __builtin_amdgcn_s_setprio(1);                                               \
    _Pragma("unroll")                                                            \
    for (int q = 0; q < 4; ++q)                                                  \
      _Pragma("unroll")                                                          \
      for (int ni = 0; ni < 4; ++ni)                                             \
        acc[(MH) * 4 + q][ni] = __builtin_amdgcn_mfma_f32_16x16x32_bf16(         \
            afr[q], bfr[ni], acc[(MH) * 4 + q][ni], 0, 0, 0);                    \
    __builtin_amdgcn_s_setprio(0);                                               \
    __builtin_amdgcn_s_barrier();                                                \
    SBAR;                                                                        \
  } while (0)

  const int NTK = K >> 6;

  // prologue: stage full tile 0 into buf0, drain, publish
  STG_A(0, 0, 0);
  STG_B(0, 0, 0);
  STG_B(1, 0, 0);
  if constexpr (AH == 2) STG_A(1, 0, 0);
  SBAR;
  asm volatile("s_waitcnt vmcnt(0)" ::: "memory");
  SBAR;
  __builtin_amdgcn_s_barrier();
  SBAR;

  if constexpr (BM == 256) {
    for (int kt = 0; kt < NTK - 1; ++kt) {
      const char* bufp = (const char*)lds + (kt & 1) * BUFB;
      int nb = (kt + 1) & 1, k1 = kt + 1;
      PHASE(0, 0, 1, 1, bufp, nb, k1);
      PHASE(0, 1, 2, 0, bufp, nb, k1);
      PHASE(1, 0, 0, 0, bufp, nb, k1);
      PHASE(1, 1, 0, 2, bufp, nb, k1);
    }
    const char* bufp = (const char*)lds + ((NTK - 1) & 1) * BUFB;
    PHASE(0, 0, 0, 3, bufp, 0, 0);
    PHASE(0, 1, 0, 0, bufp, 0, 0);
    PHASE(1, 0, 0, 0, bufp, 0, 0);
    PHASE(1, 1, 0, 0, bufp, 0, 0);
  } else {
    for (int kt = 0; kt < NTK; ++kt) {
      const char* bufp = (const char*)lds + (kt & 1) * BUFB;
      int nb = (kt + 1) & 1, k1 = kt + 1;
      int stg = (kt + 1 < NTK) ? 1 : 0;
      PHASE(0, 0, stg, 0, bufp, nb, k1);
      PHASE(1, 0, 0, 3, bufp, nb, k1);
    }
  }

  // ---------------- epilogue ----------------
  if constexpr (EPI == 0) {
    float b1v[2], b3v[2];
    int rcbase = bx * 128 + wn * 32 + (lane & 15);
#pragma unroll
    for (int ni2 = 0; ni2 < 2; ++ni2) {
      b1v[ni2] = bias1[boff + rcbase + ni2 * 16];
      b3v[ni2] = bias3[boff + rcbase + ni2 * 16];
    }
    bf16_t* Hout = (bf16_t*)Outp;
#pragma unroll
    for (int mi = 0; mi < MI; ++mi)
#pragma unroll
      for (int rg = 0; rg < 4; ++rg) {
        int Rb = ((mi >= 4) ? 128 : 0) + wm * 64 + (mi & 3) * 16;
        int rt = Rb + ((lane >> 4) << 2) + rg;
        int grow = rowstart + rt;
        float wt = 1.0f;
        if constexpr (TABLE) wt = wtlist[grow];
        size_t ob = (size_t)grow * ldOut + rcbase;
#pragma unroll
        for (int ni2 = 0; ni2 < 2; ++ni2) {
          float v1 = acc[mi][2 * ni2][rg] + b1v[ni2];
          float v3 = acc[mi][2 * ni2 + 1][rg] + b3v[ni2];
          float sg = v1 / (1.0f + __expf(-v1));
          Hout[ob + ni2 * 16] = (bf16_t)(sg * v3 * wt);
        }
      }
  } else if constexpr (EPI == 1) {
    float bv[4];
    int colbase = bx * BN + wn * 64 + (lane & 15);
#pragma unroll
    for (int ni = 0; ni < 4; ++ni) bv[ni] = bias1[boff + colbase + ni * 16];
    bf16_t* Yout = (bf16_t*)Outp;
#pragma unroll
    for (int mi = 0; mi < MI; ++mi)
#pragma unroll
      for (int rg = 0; rg < 4; ++rg) {
        int Rb = ((mi >= 4) ? 128 : 0) + wm * 64 + (mi & 3) * 16;
        int rt = Rb + ((lane >> 4) << 2) + rg;
        int grow = rowstart + rt;
        float wt = wtlist[grow];
        size_t ob = (size_t)grow * ldOut + colbase;
#pragma unroll
        for (int ni = 0; ni < 4; ++ni)
          Yout[ob + ni * 16] = (bf16_t)(acc[mi][ni][rg] + wt * bv[ni]);
      }
  } else {
    float bv[4];
    int colbase = bx * BN + wn * 64 + (lane & 15);
#pragma unroll
    for (int ni = 0; ni < 4; ++ni) bv[ni] = bias1[boff + colbase + ni * 16];
    float* Fout = (float*)Outp;
#pragma unroll
    for (int mi = 0; mi < MI; ++mi)
#pragma unroll
      for (int rg = 0; rg < 4; ++rg) {
        int Rb = ((mi >= 4) ? 128 : 0) + wm * 64 + (mi & 3) * 16;
        int rt = Rb + ((lane >> 4) << 2) + rg;
        int grow = rowstart + rt;
        size_t ob = (size_t)grow * ldOut + colbase;
#pragma unroll
        for (int ni = 0; ni < 4; ++ni)
          Fout[ob + ni * 16] = acc[mi][ni][rg] + bv[ni];
      }
  }
#undef PHASE
#undef STG_A
#undef STG_B
}

// ---------------- host ----------------
extern "C" void kernel_launch(void* const* d_in, const int* in_sizes, int n_in,
                              void* d_out, int out_size, void* d_ws, size_t ws_size,
                              hipStream_t stream) {
  const float* x   = (const float*)d_in[0];
  const float* gw  = (const float*)d_in[1];
  const float* ew1 = (const float*)d_in[2];
  const float* eb1 = (const float*)d_in[3];
  const float* ew2 = (const float*)d_in[4];
  const float* eb2 = (const float*)d_in[5];
  const float* ew3 = (const float*)d_in[6];
  const float* eb3 = (const float*)d_in[7];
  const float* sw1 = (const float*)d_in[8];
  const float* sb1 = (const float*)d_in[9];
  const float* sw2 = (const float*)d_in[10];
  const float* sb2 = (const float*)d_in[11];
  const float* sw3 = (const float*)d_in[12];
  const float* sb3 = (const float*)d_in[13];
  float* out = (float*)d_out;
  (void)ws_size;

  char* ws = (char*)d_ws;
  size_t off = 0;
  auto alloc = [&](size_t bytes) -> void* {
    off = (off + 255) & ~(size_t)255;
    void* p = ws + off;
    off += bytes;
    return p;
  };

  bf16_t* xb    = (bf16_t*)alloc((size_t)TOK * DIMD * 2);                  // 16 MB
  bf16_t* ew13i = (bf16_t*)alloc((size_t)NEXP * 2 * INTERD * DIMD * 2);    // 64 MB
  bf16_t* ew2b  = (bf16_t*)alloc((size_t)NEXP * DIMD * INTERD * 2);        // 32 MB
  bf16_t* sw13i = (bf16_t*)alloc((size_t)2 * SINTER * DIMD * 2);           // 16 MB
  bf16_t* sw2b  = (bf16_t*)alloc((size_t)DIMD * SINTER * 2);               // 4 MB
  // H union: shared Hs (8192x2048) / routed Hg (36864x1024), disjoint time windows
  bf16_t* Hun   = (bf16_t*)alloc((size_t)CAP256 * INTERD * 2);             // 72 MB
  bf16_t* Hs    = Hun;
  bf16_t* Hg    = Hun;
  // Yg (72 MB bf16) ALIASES xb+ew13i (80 MB): both dead once routed gemm1 completes;
  // cvt refills them at the start of every (replayed) call.
  bf16_t* Yg    = xb;
  int*   toklist = (int*)alloc(CAP256 * 4);
  float* wtlist  = (float*)alloc(CAP256 * 4);
  int*   offsets = (int*)alloc((NEXP + 1) * 4);
  int*   blkhist = (int*)alloc(HBLK * NEXP * 4);
  int*   blkbase = (int*)alloc(HBLK * NEXP * 4);
  int*   tile_e  = (int*)alloc(512 * 4);
  int*   tile_rs = (int*)alloc(512 * 4);
  int*   tkidx   = (int*)alloc((size_t)TOK * 4 * 4);
  float* tkwt    = (float*)alloc((size_t)TOK * 4 * 4);
  int4*  pos4    = (int4*)alloc((size_t)TOK * 16);

  init_kernel<<<(CAP256 + 255) / 256, 256, 0, stream>>>(toklist, wtlist, tile_e, tile_rs);

  cvt3_kernel<<<2048, 256, 0, stream>>>(x, xb, TOK * DIMD / 4,
                                        ew2, ew2b, NEXP * DIMD * INTERD / 4,
                                        sw2, sw2b, DIMD * SINTER / 4);
  cvt_ileave<<<2048, 256, 0, stream>>>(ew1, ew3, ew13i, NEXP * 2 * INTERD * DIMD / 4, 11);
  cvt_ileave<<<1024, 256, 0, stream>>>(sw1, sw3, sw13i, 2 * SINTER * DIMD / 4, 12);

  gate_kernel<<<TOK / 4, 256, 0, stream>>>(x, gw, tkidx, tkwt);
  hist_kernel<<<HBLK, 256, 0, stream>>>(tkidx, blkhist);
  offs_kernel<<<1, 64, 0, stream>>>(blkhist, offsets, blkbase, tile_e, tile_rs);
  scat_kernel<<<HBLK, 256, 0, stream>>>(tkidx, tkwt, blkbase, toklist, wtlist, pos4);

  // shared expert: Hs = silu(x sw1^T + sb1)*(x sw3^T + sb3); out = Hs sw2^T + sb2
  gemm8p<256, false, 0><<<dim3(2 * SINTER / 256, TOK / 256), 512, 0, stream>>>(
      xb, sw13i, sb1, sb3, Hs, nullptr, nullptr, nullptr, nullptr,
      DIMD, SINTER, 0, 0);
  gemm8p<128, false, 2><<<dim3(DIMD / 256, TOK / 128), 512, 0, stream>>>(
      Hs, sw2b, sb2, nullptr, out, nullptr, nullptr, nullptr, nullptr,
      SINTER, DIMD, 0, 0);

  // routed experts: Hg = wt * silu(.)*(.); Yg = Hg ew2^T + wt*b2 (plain bf16 store)
  gemm8p<256, true, 0><<<dim3(2 * INTERD / 256, MAXT), 512, 0, stream>>>(
      xb, ew13i, eb1, eb3, Hg, tile_e, tile_rs, toklist, wtlist,
      DIMD, INTERD, (size_t)2 * INTERD * DIMD, INTERD);
  gemm8p<256, true, 1><<<dim3(DIMD / 256, MAXT), 512, 0, stream>>>(
      Hg, ew2b, eb2, nullptr, Yg, tile_e, tile_rs, toklist, wtlist,
      INTERD, DIMD, (size_t)DIMD * INTERD, DIMD);

  // combine: out[t] += sum_k Yg[pos(t,k)]
  fuse_kernel<<<TOK, 256, 0, stream>>>(pos4, Yg, out);
}

// Round 10
// 536.745 us; speedup vs baseline: 1.3622x; 1.0218x over previous
//
#include <hip/hip_runtime.h>
#include <cstdint>
#include <cstddef>

#define TOK     8192
#define DIMD    1024
#define INTERD  1024
#define NEXP    16
#define SINTER  2048
#define CAP256  36864   // 32768 + 16*256 padding capacity
#define MAXT    144     // sum ceil(cnt_e/256) <= 128 + 16
#define HBLK    32

typedef __bf16 bf16_t;
typedef __bf16 bf16x8_t __attribute__((ext_vector_type(8)));
typedef __bf16 bf16x4_t __attribute__((ext_vector_type(4)));
typedef float  f32x4_t  __attribute__((ext_vector_type(4)));

// async global->LDS, 16B per lane; LDS dest is wave-uniform base + lane*16
__device__ __forceinline__ void gload_lds16(const bf16_t* g, bf16_t* l) {
  __builtin_amdgcn_global_load_lds((const __attribute__((address_space(1))) void*)g,
                                   (__attribute__((address_space(3))) void*)l,
                                   16, 0, 0);
}

#define SBAR __builtin_amdgcn_sched_barrier(0)

// ---------------- fp32 -> bf16 (3 tensors) + list/table init, one launch ----------------
__global__ void cvt3_kernel(const float* __restrict__ s0, bf16_t* __restrict__ d0, int n0,
                            const float* __restrict__ s1, bf16_t* __restrict__ d1, int n1,
                            const float* __restrict__ s2, bf16_t* __restrict__ d2, int n2,
                            int* __restrict__ toklist, float* __restrict__ wtlist,
                            int* __restrict__ tile_e, int* __restrict__ tile_rs) {
  int gid = blockIdx.x * blockDim.x + threadIdx.x;
  if (gid < CAP256) { toklist[gid] = -1; wtlist[gid] = 0.0f; }
  if (gid < 512)    { tile_e[gid] = -1; tile_rs[gid] = 0; }
  int total = n0 + n1 + n2;
  int stride = gridDim.x * blockDim.x;
  for (int i = gid; i < total; i += stride) {
    const float* s; bf16_t* d; int j = i;
    if (j < n0) { s = s0; d = d0; }
    else if ((j - n0) < n1) { j -= n0; s = s1; d = d1; }
    else { j -= n0 + n1; s = s2; d = d2; }
    float4 v = ((const float4*)s)[j];
    bf16x4_t o;
    o[0] = (bf16_t)v.x; o[1] = (bf16_t)v.y; o[2] = (bf16_t)v.z; o[3] = (bf16_t)v.w;
    ((bf16x4_t*)d)[j] = o;
  }
}

// ---------------- fp32 -> bf16 with 16-row W1/W3 interleave ----------------
__global__ void cvt_ileave(const float* __restrict__ s1, const float* __restrict__ s3,
                           bf16_t* __restrict__ dst, int total4, int esh) {
  int stride = gridDim.x * blockDim.x;
  int fmask = (1 << esh) - 1;
  for (int i = blockIdx.x * blockDim.x + threadIdx.x; i < total4; i += stride) {
    int k4 = i & 255;            // K=1024 -> K/4=256
    int fr = i >> 8;
    int e  = fr >> esh;
    int f  = fr & fmask;
    int p  = f >> 4, s = f & 15;
    int real = ((p >> 1) << 4) + s;
    size_t srow = ((size_t)e << (esh - 1)) + real;
    const float* src = ((p & 1) ? s3 : s1) + (srow << 10) + (k4 << 2);
    float4 v = *(const float4*)src;
    bf16x4_t o;
    o[0] = (bf16_t)v.x; o[1] = (bf16_t)v.y; o[2] = (bf16_t)v.z; o[3] = (bf16_t)v.w;
    ((bf16x4_t*)dst)[i] = o;
  }
}

// ---------------- gate: softmax -> top4 (one wave/token, no atomics) ----------------
__global__ __launch_bounds__(256)
void gate_kernel(const float* __restrict__ x, const float* __restrict__ gw,
                 int* __restrict__ tkidx, float* __restrict__ tkwt) {
  int wv = threadIdx.x >> 6, lane = threadIdx.x & 63;
  int t = blockIdx.x * 4 + wv;
  const float4* xp = (const float4*)(x + (size_t)t * DIMD + lane * 16);
  float4 xv[4];
#pragma unroll
  for (int i = 0; i < 4; ++i) xv[i] = xp[i];
  float sc[NEXP];
#pragma unroll
  for (int e = 0; e < NEXP; ++e) {
    const float4* wp = (const float4*)(gw + (size_t)e * DIMD + lane * 16);
    float s = 0.0f;
#pragma unroll
    for (int i = 0; i < 4; ++i) {
      float4 w = wp[i];
      s += xv[i].x * w.x + xv[i].y * w.y + xv[i].z * w.z + xv[i].w * w.w;
    }
    sc[e] = s;
  }
#pragma unroll
  for (int off = 32; off > 0; off >>= 1)
#pragma unroll
    for (int e = 0; e < NEXP; ++e)
      sc[e] += __shfl_xor(sc[e], off, 64);
  if (lane == 0) {
    float m = sc[0];
#pragma unroll
    for (int e = 1; e < NEXP; ++e) m = fmaxf(m, sc[e]);
    float p[NEXP], s = 0.0f;
#pragma unroll
    for (int e = 0; e < NEXP; ++e) { p[e] = __expf(sc[e] - m); s += p[e]; }
    float inv = 1.0f / s;
    unsigned used = 0;
    for (int k = 0; k < 4; ++k) {
      int best = 0; float bv = -1.0f;
#pragma unroll
      for (int e = 0; e < NEXP; ++e)
        if (!((used >> e) & 1u) && p[e] > bv) { bv = p[e]; best = e; }
      used |= 1u << best;
      tkidx[t * 4 + k] = best;
      tkwt[t * 4 + k] = bv * inv;
    }
  }
}

// ---------------- per-block histogram ----------------
__global__ __launch_bounds__(256)
void hist_kernel(const int* __restrict__ tkidx, int* __restrict__ blkhist) {
  __shared__ int h[NEXP];
  if (threadIdx.x < NEXP) h[threadIdx.x] = 0;
  __syncthreads();
  int4 v = ((const int4*)tkidx)[blockIdx.x * 256 + threadIdx.x];
  atomicAdd(&h[v.x], 1);
  atomicAdd(&h[v.y], 1);
  atomicAdd(&h[v.z], 1);
  atomicAdd(&h[v.w], 1);
  __syncthreads();
  if (threadIdx.x < NEXP) blkhist[blockIdx.x * NEXP + threadIdx.x] = h[threadIdx.x];
}

// ---------------- offsets + tile table + scatter bases (parallel scan, 1 block) ----------------
// tid = e*32 + b: lanes [0..31]/[32..63] of a wave are two experts' 32 block-counts.
__global__ __launch_bounds__(512)
void offs_kernel(const int* __restrict__ blkhist, int* __restrict__ blkbase,
                 int* __restrict__ tile_e, int* __restrict__ tile_rs) {
  int tid = threadIdx.x;
  int e = tid >> 5, b = tid & 31;
  int v = blkhist[b * NEXP + e];
  int scan = v;
#pragma unroll
  for (int d = 1; d < 32; d <<= 1) {
    int u = __shfl_up(scan, d, 32);
    if (b >= d) scan += u;
  }
  int total = __shfl(scan, 31, 32);
  int excl = scan - v;
  __shared__ int counts[NEXP], offs[NEXP];
  if (b == 31) counts[e] = total;
  __syncthreads();
  if (tid == 0) {
    int off = 0, nt = 0;
    for (int ee = 0; ee < NEXP; ++ee) {
      offs[ee] = off;
      int ntile = (counts[ee] + 255) >> 8;
      for (int i = 0; i < ntile; ++i) { tile_e[nt] = ee; tile_rs[nt] = off + (i << 8); ++nt; }
      off += ntile << 8;
    }
  }
  __syncthreads();
  blkbase[b * NEXP + e] = offs[e] + excl;
}

// ---------------- scatter (LDS cursors) + record per-token slot positions ----------------
__global__ __launch_bounds__(256)
void scat_kernel(const int* __restrict__ tkidx, const float* __restrict__ tkwt,
                 const int* __restrict__ blkbase,
                 int* __restrict__ toklist, float* __restrict__ wtlist,
                 int4* __restrict__ pos4) {
  __shared__ int cur[NEXP];
  if (threadIdx.x < NEXP) cur[threadIdx.x] = blkbase[blockIdx.x * NEXP + threadIdx.x];
  __syncthreads();
  int idx = blockIdx.x * 256 + threadIdx.x;
  int4 v = ((const int4*)tkidx)[idx];
  float4 w = ((const float4*)tkwt)[idx];
  int p0 = atomicAdd(&cur[v.x], 1); toklist[p0] = idx; wtlist[p0] = w.x;
  int p1 = atomicAdd(&cur[v.y], 1); toklist[p1] = idx; wtlist[p1] = w.y;
  int p2 = atomicAdd(&cur[v.z], 1); toklist[p2] = idx; wtlist[p2] = w.z;
  int p3 = atomicAdd(&cur[v.w], 1); toklist[p3] = idx; wtlist[p3] = w.w;
  pos4[idx] = make_int4(p0, p1, p2, p3);
}

// ---------------- fuse: out[t] += sum of 4 routed contribution rows ----------------
__global__ __launch_bounds__(256)
void fuse_kernel(const int4* __restrict__ pos4, const bf16_t* __restrict__ Yg,
                 float* __restrict__ out) {
  int t = blockIdx.x;
  int4 p = pos4[t];
  int c = threadIdx.x;   // 256 threads x float4 = 1024 cols
  float4 o = ((const float4*)(out + (size_t)t * DIMD))[c];
  bf16x4_t y0 = ((const bf16x4_t*)(Yg + (size_t)p.x * DIMD))[c];
  bf16x4_t y1 = ((const bf16x4_t*)(Yg + (size_t)p.y * DIMD))[c];
  bf16x4_t y2 = ((const bf16x4_t*)(Yg + (size_t)p.z * DIMD))[c];
  bf16x4_t y3 = ((const bf16x4_t*)(Yg + (size_t)p.w * DIMD))[c];
  o.x += (float)y0[0] + (float)y1[0] + (float)y2[0] + (float)y3[0];
  o.y += (float)y0[1] + (float)y1[1] + (float)y2[1] + (float)y3[1];
  o.z += (float)y0[2] + (float)y1[2] + (float)y2[2] + (float)y3[2];
  o.w += (float)y0[3] + (float)y1[3] + (float)y2[3] + (float)y3[3];
  ((float4*)(out + (size_t)t * DIMD))[c] = o;
}

// ============ BMx256 GEMM, BK=64, 4-phase counted-vmcnt schedule + XCD swizzle ============
// PUBLISH INVARIANT: a phase's ds_reads are issued at the TOP of the phase, so they are
// covered by the PREVIOUS wait+barrier, never the phase's own. BM=256 per K-tile:
//   ph0: read{Ah0,B} (published by prev ph3 vmcnt(2)); stage{Ah0,Bh0,Bh1}(t+1); vmcnt(6)
//   ph1: read{Ah1}   (published by ph0); stage{Ah1}(t+1)
//   ph3: vmcnt(2) publishes t+1's first 6 for next iter's ph0.
// BM=128: ph0 stage all 6 of t+1; ph1 vmcnt(0) publishes them (full drain, 2-phase).
// EPI: 0 = dual silu epilogue -> H bf16 (B is 16-row interleaved [W1;W3])
//      1 = plain bf16 store of weighted contribution (+wt*b2) into Yg
//      2 = dense fp32 write out (+b2)
template <int BM, bool TABLE, int EPI>
__global__ __launch_bounds__(512, 2)
void gemm8p(const bf16_t* __restrict__ Ag, const bf16_t* __restrict__ Bw,
            const float* __restrict__ bias1, const float* __restrict__ bias3,
            void* __restrict__ Outp,
            const int* __restrict__ tile_e, const int* __restrict__ tile_rs,
            const int* __restrict__ toklist, const float* __restrict__ wtlist,
            int K, int ldOut, size_t strideB, int biasStride) {
  constexpr int BN = 256;
  constexpr int AH = BM / 128;          // A half-tiles (1 or 2)
  constexpr int MI = BM / 32;           // acc rows per wave (4 or 8)
  constexpr int ABYTES = BM * 128;      // A region bytes per buffer
  constexpr int BUFB = ABYTES + 32768;  // bytes per buffer
  __shared__ __align__(16) bf16_t lds[BUFB];  // 2 buffers * BUFB bytes

  // ---- T1: bijective XCD-chunked swizzle (grid size is a multiple of 8) ----
  int nwg = (int)(gridDim.x * gridDim.y);
  int lin = (int)(blockIdx.y * gridDim.x + blockIdx.x);
  int sw = (lin & 7) * (nwg >> 3) + (lin >> 3);
  int bx = sw % (int)gridDim.x;
  int by = sw / (int)gridDim.x;

  int rowstart, e = 0;
  if constexpr (TABLE) {
    e = tile_e[by];
    if (e < 0) return;
    rowstart = tile_rs[by];
  } else {
    rowstart = by * BM;
  }
  const bf16_t* Bwp = Bw + (TABLE ? (size_t)e * strideB : (size_t)0);
  const int boff = TABLE ? e * biasStride : 0;

  const int tid = threadIdx.x, lane = tid & 63, wv = tid >> 6;
  const int wm = wv >> 2, wn = wv & 3;
  const int xsw = (lane & 7) << 4;          // XOR swizzle (byte bits 4-6)
  const int klo = (lane >> 4) * 16;         // k-byte offset within MFMA step

  // ---- staging source pointers (pre-swizzled global: slot = (idx&7) ^ (row&7)) ----
  const bf16_t* srcpA[4];
  const bf16_t* srcpB[4];
#pragma unroll
  for (int h = 0; h < AH; ++h)
#pragma unroll
    for (int j = 0; j < 2; ++j) {
      int idx = tid + j * 512;
      int r = h * 128 + (idx >> 3);
      int slot = (idx & 7) ^ ((idx >> 3) & 7);
      long arow;
      if constexpr (TABLE && EPI == 0) {
        int t = toklist[rowstart + r];
        arow = (t < 0) ? 0 : t;
      } else {
        arow = rowstart + r;
      }
      srcpA[h * 2 + j] = Ag + (size_t)arow * K + slot * 8;
    }
#pragma unroll
  for (int h = 0; h < 2; ++h)
#pragma unroll
    for (int j = 0; j < 2; ++j) {
      int idx = tid + j * 512;
      int r = h * 128 + (idx >> 3);
      int slot = (idx & 7) ^ ((idx >> 3) & 7);
      srcpB[h * 2 + j] = Bwp + (size_t)(bx * BN + r) * K + slot * 8;
    }

#define STG_A(H, NB, KT) do {                                                    \
    bf16_t* d_ = (bf16_t*)lds + ((NB) * BUFB + (H) * 16384) / 2 + tid * 8;       \
    gload_lds16(srcpA[(H) * 2 + 0] + (KT) * 64, d_);                             \
    gload_lds16(srcpA[(H) * 2 + 1] + (KT) * 64, d_ + 4096);                      \
  } while (0)
#define STG_B(H, NB, KT) do {                                                    \
    bf16_t* d_ = (bf16_t*)lds + ((NB) * BUFB + ABYTES + (H) * 16384) / 2 + tid * 8; \
    gload_lds16(srcpB[(H) * 2 + 0] + (KT) * 64, d_);                             \
    gload_lds16(srcpB[(H) * 2 + 1] + (KT) * 64, d_ + 4096);                      \
  } while (0)

  f32x4_t acc[MI][4] = {};
  bf16x8_t bfr[4];

  // PHASE(KS, MH, STG, WT): STG 0=none 1={Ah0,Bh0,Bh1} 2={Ah1};
  // WT 0=none 1=vmcnt(6) 2=vmcnt(2) 3=vmcnt(0)
#define PHASE(KS, MH, STG, WT, BUFP, NB, KT1) do {                               \
    bf16x8_t afr[4];                                                             \
    _Pragma("unroll")                                                            \
    for (int q = 0; q < 4; ++q) {                                                \
      int rl = wm * 64 + q * 16 + (lane & 15);                                   \
      afr[q] = *(const bf16x8_t*)((BUFP) + (MH) * 16384 +                        \
                 ((rl * 128 + (KS) * 64 + klo) ^ xsw));                          \
    }                                                                            \
    if ((MH) == 0) {                                                             \
      _Pragma("unroll")                                                          \
      for (int ni = 0; ni < 4; ++ni) {                                           \
        int ct = wn * 64 + ni * 16 + (lane & 15);                                \
        bfr[ni] = *(const bf16x8_t*)((BUFP) + ABYTES + (ct >> 7) * 16384 +       \
                   (((ct & 127) * 128 + (KS) * 64 + klo) ^ xsw));                \
      }                                                                          \
    }                                                                            \
    if ((STG) == 1) { STG_A(0, NB, KT1); STG_B(0, NB, KT1); STG_B(1, NB, KT1); } \
    else if ((STG) == 2) { STG_A(1, NB, KT1); }                                  \
    SBAR;                                                                        \
    if ((WT) == 1) asm volatile("s_waitcnt vmcnt(6)" ::: "memory");              \
    else if ((WT) == 2) asm volatile("s_waitcnt vmcnt(2)" ::: "memory");         \
    else if ((WT) == 3) asm volatile("s_waitcnt vmcnt(0)" ::: "memory");         \
    SBAR;                                                                        \
    __builtin_amdgcn_s_barrier();                                                \
    asm volatile("s_waitcnt lgkmcnt(0)" ::: "memory");                           \
    SBAR;                                                                        \
    __builtin_amdgcn_s_setprio(1);                                               \
    _Pragma("unroll")                                                            \
    for (int q = 0; q < 4; ++q)                                                  \
      _Pragma("unroll")                                                          \
      for (int ni = 0; ni < 4; ++ni)                                             \
        acc[(MH) * 4 + q][ni] = __builtin_amdgcn_mfma_f32_16x16x32_bf16(         \
            afr[q], bfr[ni], acc[(MH) * 4 + q][ni], 0, 0, 0);                    \
    __builtin_amdgcn_s_setprio(0);                                               \
    __builtin_amdgcn_s_barrier();                                                \
    SBAR;                                                                        \
  } while (0)

  const int NTK = K >> 6;

  // prologue: stage full tile 0 into buf0, drain, publish
  STG_A(0, 0, 0);
  STG_B(0, 0, 0);
  STG_B(1, 0, 0);
  if constexpr (AH == 2) STG_A(1, 0, 0);
  SBAR;
  asm volatile("s_waitcnt vmcnt(0)" ::: "memory");
  SBAR;
  __builtin_amdgcn_s_barrier();
  SBAR;

  if constexpr (BM == 256) {
    for (int kt = 0; kt < NTK - 1; ++kt) {
      const char* bufp = (const char*)lds + (kt & 1) * BUFB;
      int nb = (kt + 1) & 1, k1 = kt + 1;
      PHASE(0, 0, 1, 1, bufp, nb, k1);
      PHASE(0, 1, 2, 0, bufp, nb, k1);
      PHASE(1, 0, 0, 0, bufp, nb, k1);
      PHASE(1, 1, 0, 2, bufp, nb, k1);
    }
    const char* bufp = (const char*)lds + ((NTK - 1) & 1) * BUFB;
    PHASE(0, 0, 0, 3, bufp, 0, 0);
    PHASE(0, 1, 0, 0, bufp, 0, 0);
    PHASE(1, 0, 0, 0, bufp, 0, 0);
    PHASE(1, 1, 0, 0, bufp, 0, 0);
  } else {
    for (int kt = 0; kt < NTK; ++kt) {
      const char* bufp = (const char*)lds + (kt & 1) * BUFB;
      int nb = (kt + 1) & 1, k1 = kt + 1;
      int stg = (kt + 1 < NTK) ? 1 : 0;
      PHASE(0, 0, stg, 0, bufp, nb, k1);
      PHASE(1, 0, 0, 3, bufp, nb, k1);
    }
  }

  // ---------------- epilogue ----------------
  if constexpr (EPI == 0) {
    float b1v[2], b3v[2];
    int rcbase = bx * 128 + wn * 32 + (lane & 15);
#pragma unroll
    for (int ni2 = 0; ni2 < 2; ++ni2) {
      b1v[ni2] = bias1[boff + rcbase + ni2 * 16];
      b3v[ni2] = bias3[boff + rcbase + ni2 * 16];
    }
    bf16_t* Hout = (bf16_t*)Outp;
#pragma unroll
    for (int mi = 0; mi < MI; ++mi)
#pragma unroll
      for (int rg = 0; rg < 4; ++rg) {
        int Rb = ((mi >= 4) ? 128 : 0) + wm * 64 + (mi & 3) * 16;
        int rt = Rb + ((lane >> 4) << 2) + rg;
        int grow = rowstart + rt;
        float wt = 1.0f;
        if constexpr (TABLE) wt = wtlist[grow];
        size_t ob = (size_t)grow * ldOut + rcbase;
#pragma unroll
        for (int ni2 = 0; ni2 < 2; ++ni2) {
          float v1 = acc[mi][2 * ni2][rg] + b1v[ni2];
          float v3 = acc[mi][2 * ni2 + 1][rg] + b3v[ni2];
          float sg = v1 / (1.0f + __expf(-v1));
          Hout[ob + ni2 * 16] = (bf16_t)(sg * v3 * wt);
        }
      }
  } else if constexpr (EPI == 1) {
    float bv[4];
    int colbase = bx * BN + wn * 64 + (lane & 15);
#pragma unroll
    for (int ni = 0; ni < 4; ++ni) bv[ni] = bias1[boff + colbase + ni * 16];
    bf16_t* Yout = (bf16_t*)Outp;
#pragma unroll
    for (int mi = 0; mi < MI; ++mi)
#pragma unroll
      for (int rg = 0; rg < 4; ++rg) {
        int Rb = ((mi >= 4) ? 128 : 0) + wm * 64 + (mi & 3) * 16;
        int rt = Rb + ((lane >> 4) << 2) + rg;
        int grow = rowstart + rt;
        float wt = wtlist[grow];
        size_t ob = (size_t)grow * ldOut + colbase;
#pragma unroll
        for (int ni = 0; ni < 4; ++ni)
          Yout[ob + ni * 16] = (bf16_t)(acc[mi][ni][rg] + wt * bv[ni]);
      }
  } else {
    float bv[4];
    int colbase = bx * BN + wn * 64 + (lane & 15);
#pragma unroll
    for (int ni = 0; ni < 4; ++ni) bv[ni] = bias1[boff + colbase + ni * 16];
    float* Fout = (float*)Outp;
#pragma unroll
    for (int mi = 0; mi < MI; ++mi)
#pragma unroll
      for (int rg = 0; rg < 4; ++rg) {
        int Rb = ((mi >= 4) ? 128 : 0) + wm * 64 + (mi & 3) * 16;
        int rt = Rb + ((lane >> 4) << 2) + rg;
        int grow = rowstart + rt;
        size_t ob = (size_t)grow * ldOut + colbase;
#pragma unroll
        for (int ni = 0; ni < 4; ++ni)
          Fout[ob + ni * 16] = acc[mi][ni][rg] + bv[ni];
      }
  }
#undef PHASE
#undef STG_A
#undef STG_B
}

// ---------------- host ----------------
extern "C" void kernel_launch(void* const* d_in, const int* in_sizes, int n_in,
                              void* d_out, int out_size, void* d_ws, size_t ws_size,
                              hipStream_t stream) {
  const float* x   = (const float*)d_in[0];
  const float* gw  = (const float*)d_in[1];
  const float* ew1 = (const float*)d_in[2];
  const float* eb1 = (const float*)d_in[3];
  const float* ew2 = (const float*)d_in[4];
  const float* eb2 = (const float*)d_in[5];
  const float* ew3 = (const float*)d_in[6];
  const float* eb3 = (const float*)d_in[7];
  const float* sw1 = (const float*)d_in[8];
  const float* sb1 = (const float*)d_in[9];
  const float* sw2 = (const float*)d_in[10];
  const float* sb2 = (const float*)d_in[11];
  const float* sw3 = (const float*)d_in[12];
  const float* sb3 = (const float*)d_in[13];
  float* out = (float*)d_out;
  (void)ws_size;

  char* ws = (char*)d_ws;
  size_t off = 0;
  auto alloc = [&](size_t bytes) -> void* {
    off = (off + 255) & ~(size_t)255;
    void* p = ws + off;
    off += bytes;
    return p;
  };

  bf16_t* xb    = (bf16_t*)alloc((size_t)TOK * DIMD * 2);                  // 16 MB
  bf16_t* ew13i = (bf16_t*)alloc((size_t)NEXP * 2 * INTERD * DIMD * 2);    // 64 MB
  bf16_t* ew2b  = (bf16_t*)alloc((size_t)NEXP * DIMD * INTERD * 2);        // 32 MB
  bf16_t* sw13i = (bf16_t*)alloc((size_t)2 * SINTER * DIMD * 2);           // 8 MB
  bf16_t* sw2b  = (bf16_t*)alloc((size_t)DIMD * SINTER * 2);               // 4 MB
  // H union: shared Hs (8192x2048) / routed Hg (36864x1024), disjoint time windows
  bf16_t* Hun   = (bf16_t*)alloc((size_t)CAP256 * INTERD * 2);             // 72 MB
  bf16_t* Hs    = Hun;
  bf16_t* Hg    = Hun;
  // Yg (72 MB bf16) ALIASES xb+ew13i (80 MB): both dead once routed gemm1 completes;
  // cvt refills them at the start of every (replayed) call.
  bf16_t* Yg    = xb;
  int*   toklist = (int*)alloc(CAP256 * 4);
  float* wtlist  = (float*)alloc(CAP256 * 4);
  int*   blkhist = (int*)alloc(HBLK * NEXP * 4);
  int*   blkbase = (int*)alloc(HBLK * NEXP * 4);
  int*   tile_e  = (int*)alloc(512 * 4);
  int*   tile_rs = (int*)alloc(512 * 4);
  int*   tkidx   = (int*)alloc((size_t)TOK * 4 * 4);
  float* tkwt    = (float*)alloc((size_t)TOK * 4 * 4);
  int4*  pos4    = (int4*)alloc((size_t)TOK * 16);

  // cvt3 also initializes toklist/wtlist/tile tables (grid covers CAP256 threads)
  cvt3_kernel<<<2048, 256, 0, stream>>>(x, xb, TOK * DIMD / 4,
                                        ew2, ew2b, NEXP * DIMD * INTERD / 4,
                                        sw2, sw2b, DIMD * SINTER / 4,
                                        toklist, wtlist, tile_e, tile_rs);
  cvt_ileave<<<2048, 256, 0, stream>>>(ew1, ew3, ew13i, NEXP * 2 * INTERD * DIMD / 4, 11);
  cvt_ileave<<<1024, 256, 0, stream>>>(sw1, sw3, sw13i, 2 * SINTER * DIMD / 4, 12);

  gate_kernel<<<TOK / 4, 256, 0, stream>>>(x, gw, tkidx, tkwt);
  hist_kernel<<<HBLK, 256, 0, stream>>>(tkidx, blkhist);
  offs_kernel<<<1, 512, 0, stream>>>(blkhist, blkbase, tile_e, tile_rs);
  scat_kernel<<<HBLK, 256, 0, stream>>>(tkidx, tkwt, blkbase, toklist, wtlist, pos4);

  // shared expert: Hs = silu(x sw1^T + sb1)*(x sw3^T + sb3); out = Hs sw2^T + sb2
  gemm8p<256, false, 0><<<dim3(2 * SINTER / 256, TOK / 256), 512, 0, stream>>>(
      xb, sw13i, sb1, sb3, Hs, nullptr, nullptr, nullptr, nullptr,
      DIMD, SINTER, 0, 0);
  gemm8p<128, false, 2><<<dim3(DIMD / 256, TOK / 128), 512, 0, stream>>>(
      Hs, sw2b, sb2, nullptr, out, nullptr, nullptr, nullptr, nullptr,
      SINTER, DIMD, 0, 0);

  // routed experts: Hg = wt * silu(.)*(.); Yg = Hg ew2^T + wt*b2 (plain bf16 store)
  gemm8p<256, true, 0><<<dim3(2 * INTERD / 256, MAXT), 512, 0, stream>>>(
      xb, ew13i, eb1, eb3, Hg, tile_e, tile_rs, toklist, wtlist,
      DIMD, INTERD, (size_t)2 * INTERD * DIMD, INTERD);
  gemm8p<256, true, 1><<<dim3(DIMD / 256, MAXT), 512, 0, stream>>>(
      Hg, ew2b, eb2, nullptr, Yg, tile_e, tile_rs, toklist, wtlist,
      INTERD, DIMD, (size_t)DIMD * INTERD, DIMD);

  // combine: out[t] += sum_k Yg[pos(t,k)]
  fuse_kernel<<<TOK, 256, 0, stream>>>(pos4, Yg, out);
}

// Round 11
// 527.986 us; speedup vs baseline: 1.3848x; 1.0166x over previous
//
#include <hip/hip_runtime.h>
#include <cstdint>
#include <cstddef>

#define TOK     8192
#define DIMD    1024
#define INTERD  1024
#define NEXP    16
#define SINTER  2048
#define CAP256  36864   // 32768 + 16*256 padding capacity
#define MAXT    144     // sum ceil(cnt_e/256) <= 128 + 16
#define HBLK    32

typedef __bf16 bf16_t;
typedef __bf16 bf16x8_t __attribute__((ext_vector_type(8)));
typedef __bf16 bf16x4_t __attribute__((ext_vector_type(4)));
typedef float  f32x4_t  __attribute__((ext_vector_type(4)));

// async global->LDS, 16B per lane; LDS dest is wave-uniform base + lane*16
__device__ __forceinline__ void gload_lds16(const bf16_t* g, bf16_t* l) {
  __builtin_amdgcn_global_load_lds((const __attribute__((address_space(1))) void*)g,
                                   (__attribute__((address_space(3))) void*)l,
                                   16, 0, 0);
}

#define SBAR __builtin_amdgcn_sched_barrier(0)

// ---------------- fp32 -> bf16 (3 tensors) + list/table init, one launch ----------------
__global__ void cvt3_kernel(const float* __restrict__ s0, bf16_t* __restrict__ d0, int n0,
                            const float* __restrict__ s1, bf16_t* __restrict__ d1, int n1,
                            const float* __restrict__ s2, bf16_t* __restrict__ d2, int n2,
                            int* __restrict__ toklist, float* __restrict__ wtlist,
                            int* __restrict__ tile_e, int* __restrict__ tile_rs) {
  int gid = blockIdx.x * blockDim.x + threadIdx.x;
  if (gid < CAP256) { toklist[gid] = -1; wtlist[gid] = 0.0f; }
  if (gid < 512)    { tile_e[gid] = -1; tile_rs[gid] = 0; }
  int total = n0 + n1 + n2;
  int stride = gridDim.x * blockDim.x;
  for (int i = gid; i < total; i += stride) {
    const float* s; bf16_t* d; int j = i;
    if (j < n0) { s = s0; d = d0; }
    else if ((j - n0) < n1) { j -= n0; s = s1; d = d1; }
    else { j -= n0 + n1; s = s2; d = d2; }
    float4 v = ((const float4*)s)[j];
    bf16x4_t o;
    o[0] = (bf16_t)v.x; o[1] = (bf16_t)v.y; o[2] = (bf16_t)v.z; o[3] = (bf16_t)v.w;
    ((bf16x4_t*)d)[j] = o;
  }
}

// ---------------- fp32 -> bf16 with 16-row W1/W3 interleave ----------------
__global__ void cvt_ileave(const float* __restrict__ s1, const float* __restrict__ s3,
                           bf16_t* __restrict__ dst, int total4, int esh) {
  int stride = gridDim.x * blockDim.x;
  int fmask = (1 << esh) - 1;
  for (int i = blockIdx.x * blockDim.x + threadIdx.x; i < total4; i += stride) {
    int k4 = i & 255;            // K=1024 -> K/4=256
    int fr = i >> 8;
    int e  = fr >> esh;
    int f  = fr & fmask;
    int p  = f >> 4, s = f & 15;
    int real = ((p >> 1) << 4) + s;
    size_t srow = ((size_t)e << (esh - 1)) + real;
    const float* src = ((p & 1) ? s3 : s1) + (srow << 10) + (k4 << 2);
    float4 v = *(const float4*)src;
    bf16x4_t o;
    o[0] = (bf16_t)v.x; o[1] = (bf16_t)v.y; o[2] = (bf16_t)v.z; o[3] = (bf16_t)v.w;
    ((bf16x4_t*)dst)[i] = o;
  }
}

// ---------------- gate: softmax -> top4 (one wave/token, no atomics) ----------------
__global__ __launch_bounds__(256)
void gate_kernel(const float* __restrict__ x, const float* __restrict__ gw,
                 int* __restrict__ tkidx, float* __restrict__ tkwt) {
  int wv = threadIdx.x >> 6, lane = threadIdx.x & 63;
  int t = blockIdx.x * 4 + wv;
  const float4* xp = (const float4*)(x + (size_t)t * DIMD + lane * 16);
  float4 xv[4];
#pragma unroll
  for (int i = 0; i < 4; ++i) xv[i] = xp[i];
  float sc[NEXP];
#pragma unroll
  for (int e = 0; e < NEXP; ++e) {
    const float4* wp = (const float4*)(gw + (size_t)e * DIMD + lane * 16);
    float s = 0.0f;
#pragma unroll
    for (int i = 0; i < 4; ++i) {
      float4 w = wp[i];
      s += xv[i].x * w.x + xv[i].y * w.y + xv[i].z * w.z + xv[i].w * w.w;
    }
    sc[e] = s;
  }
#pragma unroll
  for (int off = 32; off > 0; off >>= 1)
#pragma unroll
    for (int e = 0; e < NEXP; ++e)
      sc[e] += __shfl_xor(sc[e], off, 64);
  if (lane == 0) {
    float m = sc[0];
#pragma unroll
    for (int e = 1; e < NEXP; ++e) m = fmaxf(m, sc[e]);
    float p[NEXP], s = 0.0f;
#pragma unroll
    for (int e = 0; e < NEXP; ++e) { p[e] = __expf(sc[e] - m); s += p[e]; }
    float inv = 1.0f / s;
    unsigned used = 0;
    for (int k = 0; k < 4; ++k) {
      int best = 0; float bv = -1.0f;
#pragma unroll
      for (int e = 0; e < NEXP; ++e)
        if (!((used >> e) & 1u) && p[e] > bv) { bv = p[e]; best = e; }
      used |= 1u << best;
      tkidx[t * 4 + k] = best;
      tkwt[t * 4 + k] = bv * inv;
    }
  }
}

// ---------------- per-block histogram ----------------
__global__ __launch_bounds__(256)
void hist_kernel(const int* __restrict__ tkidx, int* __restrict__ blkhist) {
  __shared__ int h[NEXP];
  if (threadIdx.x < NEXP) h[threadIdx.x] = 0;
  __syncthreads();
  int4 v = ((const int4*)tkidx)[blockIdx.x * 256 + threadIdx.x];
  atomicAdd(&h[v.x], 1);
  atomicAdd(&h[v.y], 1);
  atomicAdd(&h[v.z], 1);
  atomicAdd(&h[v.w], 1);
  __syncthreads();
  if (threadIdx.x < NEXP) blkhist[blockIdx.x * NEXP + threadIdx.x] = h[threadIdx.x];
}

// ---------------- offsets + tile table + scatter bases (parallel scan, 1 block) ----------------
__global__ __launch_bounds__(512)
void offs_kernel(const int* __restrict__ blkhist, int* __restrict__ blkbase,
                 int* __restrict__ tile_e, int* __restrict__ tile_rs) {
  int tid = threadIdx.x;
  int e = tid >> 5, b = tid & 31;
  int v = blkhist[b * NEXP + e];
  int scan = v;
#pragma unroll
  for (int d = 1; d < 32; d <<= 1) {
    int u = __shfl_up(scan, d, 32);
    if (b >= d) scan += u;
  }
  int total = __shfl(scan, 31, 32);
  int excl = scan - v;
  __shared__ int counts[NEXP], offs[NEXP];
  if (b == 31) counts[e] = total;
  __syncthreads();
  if (tid == 0) {
    int off = 0, nt = 0;
    for (int ee = 0; ee < NEXP; ++ee) {
      offs[ee] = off;
      int ntile = (counts[ee] + 255) >> 8;
      for (int i = 0; i < ntile; ++i) { tile_e[nt] = ee; tile_rs[nt] = off + (i << 8); ++nt; }
      off += ntile << 8;
    }
  }
  __syncthreads();
  blkbase[b * NEXP + e] = offs[e] + excl;
}

// ---------------- scatter (LDS cursors) + record per-token slot positions ----------------
__global__ __launch_bounds__(256)
void scat_kernel(const int* __restrict__ tkidx, const float* __restrict__ tkwt,
                 const int* __restrict__ blkbase,
                 int* __restrict__ toklist, float* __restrict__ wtlist,
                 int4* __restrict__ pos4) {
  __shared__ int cur[NEXP];
  if (threadIdx.x < NEXP) cur[threadIdx.x] = blkbase[blockIdx.x * NEXP + threadIdx.x];
  __syncthreads();
  int idx = blockIdx.x * 256 + threadIdx.x;
  int4 v = ((const int4*)tkidx)[idx];
  float4 w = ((const float4*)tkwt)[idx];
  int p0 = atomicAdd(&cur[v.x], 1); toklist[p0] = idx; wtlist[p0] = w.x;
  int p1 = atomicAdd(&cur[v.y], 1); toklist[p1] = idx; wtlist[p1] = w.y;
  int p2 = atomicAdd(&cur[v.z], 1); toklist[p2] = idx; wtlist[p2] = w.z;
  int p3 = atomicAdd(&cur[v.w], 1); toklist[p3] = idx; wtlist[p3] = w.w;
  pos4[idx] = make_int4(p0, p1, p2, p3);
}

// ---------------- fuse: out[t] += sum of 4 routed contribution rows ----------------
__global__ __launch_bounds__(256)
void fuse_kernel(const int4* __restrict__ pos4, const bf16_t* __restrict__ Yg,
                 float* __restrict__ out) {
  int t = blockIdx.x;
  int4 p = pos4[t];
  int c = threadIdx.x;   // 256 threads x float4 = 1024 cols
  float4 o = ((const float4*)(out + (size_t)t * DIMD))[c];
  bf16x4_t y0 = ((const bf16x4_t*)(Yg + (size_t)p.x * DIMD))[c];
  bf16x4_t y1 = ((const bf16x4_t*)(Yg + (size_t)p.y * DIMD))[c];
  bf16x4_t y2 = ((const bf16x4_t*)(Yg + (size_t)p.z * DIMD))[c];
  bf16x4_t y3 = ((const bf16x4_t*)(Yg + (size_t)p.w * DIMD))[c];
  o.x += (float)y0[0] + (float)y1[0] + (float)y2[0] + (float)y3[0];
  o.y += (float)y0[1] + (float)y1[1] + (float)y2[1] + (float)y3[1];
  o.z += (float)y0[2] + (float)y1[2] + (float)y2[2] + (float)y3[2];
  o.w += (float)y0[3] + (float)y1[3] + (float)y2[3] + (float)y3[3];
  ((float4*)(out + (size_t)t * DIMD))[c] = o;
}

// ============ BMx256 GEMM, BK=64, counted-vmcnt schedules + XCD swizzle ============
// PUBLISH INVARIANT: ds_reads of a tile are only issued after a wait+barrier pair that
// guarantees ALL waves' staging of that tile has landed.
// BM=256 (4 phases/K-tile, reads at phase top, publisher = previous wait+barrier):
//   ph0: read{Ah0,B}; stage{Ah0,Bh0,Bh1}(t+1); vmcnt(6)  [tile t fully landed]
//   ph1: read{Ah1}; stage{Ah1}(t+1)
//   ph3: vmcnt(2) publishes t+1's first 6 for next iter's ph0.
// BM=128 (2 phases/K-tile, counted, reads AFTER the wait):
//   per tile: stage all 6 of t+1; vmcnt(6) [tile t landed, t+1 in flight]; barrier;
//   ph0 read ks0+MFMA; barrier; ph1 read ks1+MFMA; barrier. Last tile: vmcnt(0).
// EPI: 0 = dual silu epilogue -> H bf16 (B is 16-row interleaved [W1;W3])
//      1 = plain bf16 store of weighted contribution (+wt*b2) into Yg
//      2 = dense fp32 write out (+b2)
template <int BM, bool TABLE, int EPI>
__global__ __launch_bounds__(512, 2)
void gemm8p(const bf16_t* __restrict__ Ag, const bf16_t* __restrict__ Bw,
            const float* __restrict__ bias1, const float* __restrict__ bias3,
            void* __restrict__ Outp,
            const int* __restrict__ tile_e, const int* __restrict__ tile_rs,
            const int* __restrict__ toklist, const float* __restrict__ wtlist,
            int K, int ldOut, size_t strideB, int biasStride) {
  constexpr int BN = 256;
  constexpr int AH = BM / 128;          // A half-tiles (1 or 2)
  constexpr int MI = BM / 32;           // acc rows per wave (4 or 8)
  constexpr int ABYTES = BM * 128;      // A region bytes per buffer
  constexpr int BUFB = ABYTES + 32768;  // bytes per buffer
  __shared__ __align__(16) bf16_t lds[BUFB];  // 2 buffers * BUFB bytes

  // ---- T1: bijective XCD-chunked swizzle (grid size is a multiple of 8) ----
  int nwg = (int)(gridDim.x * gridDim.y);
  int lin = (int)(blockIdx.y * gridDim.x + blockIdx.x);
  int sw = (lin & 7) * (nwg >> 3) + (lin >> 3);
  int bx = sw % (int)gridDim.x;
  int by = sw / (int)gridDim.x;

  int rowstart, e = 0;
  if constexpr (TABLE) {
    e = tile_e[by];
    if (e < 0) return;
    rowstart = tile_rs[by];
  } else {
    rowstart = by * BM;
  }
  const bf16_t* Bwp = Bw + (TABLE ? (size_t)e * strideB : (size_t)0);
  const int boff = TABLE ? e * biasStride : 0;

  const int tid = threadIdx.x, lane = tid & 63, wv = tid >> 6;
  const int wm = wv >> 2, wn = wv & 3;
  const int xsw = (lane & 7) << 4;          // XOR swizzle (byte bits 4-6)
  const int klo = (lane >> 4) * 16;         // k-byte offset within MFMA step

  // ---- staging source pointers (pre-swizzled global: slot = (idx&7) ^ (row&7)) ----
  const bf16_t* srcpA[4];
  const bf16_t* srcpB[4];
#pragma unroll
  for (int h = 0; h < AH; ++h)
#pragma unroll
    for (int j = 0; j < 2; ++j) {
      int idx = tid + j * 512;
      int r = h * 128 + (idx >> 3);
      int slot = (idx & 7) ^ ((idx >> 3) & 7);
      long arow;
      if constexpr (TABLE && EPI == 0) {
        int t = toklist[rowstart + r];
        arow = (t < 0) ? 0 : t;
      } else {
        arow = rowstart + r;
      }
      srcpA[h * 2 + j] = Ag + (size_t)arow * K + slot * 8;
    }
#pragma unroll
  for (int h = 0; h < 2; ++h)
#pragma unroll
    for (int j = 0; j < 2; ++j) {
      int idx = tid + j * 512;
      int r = h * 128 + (idx >> 3);
      int slot = (idx & 7) ^ ((idx >> 3) & 7);
      srcpB[h * 2 + j] = Bwp + (size_t)(bx * BN + r) * K + slot * 8;
    }

#define STG_A(H, NB, KT) do {                                                    \
    bf16_t* d_ = (bf16_t*)lds + ((NB) * BUFB + (H) * 16384) / 2 + tid * 8;       \
    gload_lds16(srcpA[(H) * 2 + 0] + (KT) * 64, d_);                             \
    gload_lds16(srcpA[(H) * 2 + 1] + (KT) * 64, d_ + 4096);                      \
  } while (0)
#define STG_B(H, NB, KT) do {                                                    \
    bf16_t* d_ = (bf16_t*)lds + ((NB) * BUFB + ABYTES + (H) * 16384) / 2 + tid * 8; \
    gload_lds16(srcpB[(H) * 2 + 0] + (KT) * 64, d_);                             \
    gload_lds16(srcpB[(H) * 2 + 1] + (KT) * 64, d_ + 4096);                      \
  } while (0)

  f32x4_t acc[MI][4] = {};
  bf16x8_t bfr[4];

  // PHASE(KS, MH, STG, WT): reads at top (publisher = previous wait+barrier).
  // STG 0=none 1={Ah0,Bh0,Bh1} 2={Ah1}; WT 0=none 1=vmcnt(6) 2=vmcnt(2) 3=vmcnt(0)
#define PHASE(KS, MH, STG, WT, BUFP, NB, KT1) do {                               \
    bf16x8_t afr[4];                                                             \
    _Pragma("unroll")                                                            \
    for (int q = 0; q < 4; ++q) {                                                \
      int rl = wm * 64 + q * 16 + (lane & 15);                                   \
      afr[q] = *(const bf16x8_t*)((BUFP) + (MH) * 16384 +                        \
                 ((rl * 128 + (KS) * 64 + klo) ^ xsw));                          \
    }                                                                            \
    if ((MH) == 0) {                                                             \
      _Pragma("unroll")                                                          \
      for (int ni = 0; ni < 4; ++ni) {                                           \
        int ct = wn * 64 + ni * 16 + (lane & 15);                                \
        bfr[ni] = *(const bf16x8_t*)((BUFP) + ABYTES + (ct >> 7) * 16384 +       \
                   (((ct & 127) * 128 + (KS) * 64 + klo) ^ xsw));                \
      }                                                                          \
    }                                                                            \
    if ((STG) == 1) { STG_A(0, NB, KT1); STG_B(0, NB, KT1); STG_B(1, NB, KT1); } \
    else if ((STG) == 2) { STG_A(1, NB, KT1); }                                  \
    SBAR;                                                                        \
    if ((WT) == 1) asm volatile("s_waitcnt vmcnt(6)" ::: "memory");              \
    else if ((WT) == 2) asm volatile("s_waitcnt vmcnt(2)" ::: "memory");         \
    else if ((WT) == 3) asm volatile("s_waitcnt vmcnt(0)" ::: "memory");         \
    SBAR;                                                                        \
    __builtin_amdgcn_s_barrier();                                                \
    asm volatile("s_waitcnt lgkmcnt(0)" ::: "memory");                           \
    SBAR;                                                                        \
    __builtin_amdgcn_s_setprio(1);                                               \
    _Pragma("unroll")                                                            \
    for (int q = 0; q < 4; ++q)                                                  \
      _Pragma("unroll")                                                          \
      for (int ni = 0; ni < 4; ++ni)                                             \
        acc[(MH) * 4 + q][ni] = __builtin_amdgcn_mfma_f32_16x16x32_bf16(         \
            afr[q], bfr[ni], acc[(MH) * 4 + q][ni], 0, 0, 0);                    \
    __builtin_amdgcn_s_setprio(0);                                               \
    __builtin_amdgcn_s_barrier();                                                \
    SBAR;                                                                        \
  } while (0)

  // BM=128 phase: reads AFTER the per-tile publish barrier (issued here), then MFMA.
#define PH128(KS, BUFP) do {                                                     \
    bf16x8_t afr[4];                                                             \
    _Pragma("unroll")                                                            \
    for (int q = 0; q < 4; ++q) {                                                \
      int rl = wm * 64 + q * 16 + (lane & 15);                                   \
      afr[q] = *(const bf16x8_t*)((BUFP) +                                       \
                 ((rl * 128 + (KS) * 64 + klo) ^ xsw));                          \
    }                                                                            \
    _Pragma("unroll")                                                            \
    for (int ni = 0; ni < 4; ++ni) {                                             \
      int ct = wn * 64 + ni * 16 + (lane & 15);                                  \
      bfr[ni] = *(const bf16x8_t*)((BUFP) + ABYTES + (ct >> 7) * 16384 +         \
                 (((ct & 127) * 128 + (KS) * 64 + klo) ^ xsw));                  \
    }                                                                            \
    asm volatile("s_waitcnt lgkmcnt(0)" ::: "memory");                           \
    SBAR;                                                                        \
    __builtin_amdgcn_s_setprio(1);                                               \
    _Pragma("unroll")                                                            \
    for (int q = 0; q < 4; ++q)                                                  \
      _Pragma("unroll")                                                          \
      for (int ni = 0; ni < 4; ++ni)                                             \
        acc[q][ni] = __builtin_amdgcn_mfma_f32_16x16x32_bf16(                    \
            afr[q], bfr[ni], acc[q][ni], 0, 0, 0);                               \
    __builtin_amdgcn_s_setprio(0);                                               \
    __builtin_amdgcn_s_barrier();                                                \
    SBAR;                                                                        \
  } while (0)

  const int NTK = K >> 6;

  // prologue: stage full tile 0 into buf0, drain, publish
  STG_A(0, 0, 0);
  STG_B(0, 0, 0);
  STG_B(1, 0, 0);
  if constexpr (AH == 2) STG_A(1, 0, 0);
  SBAR;
  asm volatile("s_waitcnt vmcnt(0)" ::: "memory");
  SBAR;
  __builtin_amdgcn_s_barrier();
  SBAR;

  if constexpr (BM == 256) {
    for (int kt = 0; kt < NTK - 1; ++kt) {
      const char* bufp = (const char*)lds + (kt & 1) * BUFB;
      int nb = (kt + 1) & 1, k1 = kt + 1;
      PHASE(0, 0, 1, 1, bufp, nb, k1);
      PHASE(0, 1, 2, 0, bufp, nb, k1);
      PHASE(1, 0, 0, 0, bufp, nb, k1);
      PHASE(1, 1, 0, 2, bufp, nb, k1);
    }
    const char* bufp = (const char*)lds + ((NTK - 1) & 1) * BUFB;
    PHASE(0, 0, 0, 3, bufp, 0, 0);
    PHASE(0, 1, 0, 0, bufp, 0, 0);
    PHASE(1, 0, 0, 0, bufp, 0, 0);
    PHASE(1, 1, 0, 0, bufp, 0, 0);
  } else {
    // counted-vmcnt 2-phase: ledger — at iter entry, outstanding = 6 (tile kt's loads,
    // staged at iter kt-1). Stage t+1 (12 out), vmcnt(6) -> tile kt landed; barrier
    // publishes; reads follow. End-of-ph1 barrier protects buf[(kt+1)&1] restage.
    for (int kt = 0; kt < NTK; ++kt) {
      const char* bufp = (const char*)lds + (kt & 1) * BUFB;
      if (kt + 1 < NTK) {
        int nb = (kt + 1) & 1, k1 = kt + 1;
        STG_A(0, nb, k1); STG_B(0, nb, k1); STG_B(1, nb, k1);
        SBAR;
        asm volatile("s_waitcnt vmcnt(6)" ::: "memory");
      } else {
        SBAR;
        asm volatile("s_waitcnt vmcnt(0)" ::: "memory");
      }
      SBAR;
      __builtin_amdgcn_s_barrier();
      SBAR;
      PH128(0, bufp);
      PH128(1, bufp);
    }
  }

  // ---------------- epilogue ----------------
  if constexpr (EPI == 0) {
    float b1v[2], b3v[2];
    int rcbase = bx * 128 + wn * 32 + (lane & 15);
#pragma unroll
    for (int ni2 = 0; ni2 < 2; ++ni2) {
      b1v[ni2] = bias1[boff + rcbase + ni2 * 16];
      b3v[ni2] = bias3[boff + rcbase + ni2 * 16];
    }
    bf16_t* Hout = (bf16_t*)Outp;
#pragma unroll
    for (int mi = 0; mi < MI; ++mi)
#pragma unroll
      for (int rg = 0; rg < 4; ++rg) {
        int Rb = ((mi >= 4) ? 128 : 0) + wm * 64 + (mi & 3) * 16;
        int rt = Rb + ((lane >> 4) << 2) + rg;
        int grow = rowstart + rt;
        float wt = 1.0f;
        if constexpr (TABLE) wt = wtlist[grow];
        size_t ob = (size_t)grow * ldOut + rcbase;
#pragma unroll
        for (int ni2 = 0; ni2 < 2; ++ni2) {
          float v1 = acc[mi][2 * ni2][rg] + b1v[ni2];
          float v3 = acc[mi][2 * ni2 + 1][rg] + b3v[ni2];
          float sg = v1 / (1.0f + __expf(-v1));
          Hout[ob + ni2 * 16] = (bf16_t)(sg * v3 * wt);
        }
      }
  } else if constexpr (EPI == 1) {
    float bv[4];
    int colbase = bx * BN + wn * 64 + (lane & 15);
#pragma unroll
    for (int ni = 0; ni < 4; ++ni) bv[ni] = bias1[boff + colbase + ni * 16];
    bf16_t* Yout = (bf16_t*)Outp;
#pragma unroll
    for (int mi = 0; mi < MI; ++mi)
#pragma unroll
      for (int rg = 0; rg < 4; ++rg) {
        int Rb = ((mi >= 4) ? 128 : 0) + wm * 64 + (mi & 3) * 16;
        int rt = Rb + ((lane >> 4) << 2) + rg;
        int grow = rowstart + rt;
        float wt = wtlist[grow];
        size_t ob = (size_t)grow * ldOut + colbase;
#pragma unroll
        for (int ni = 0; ni < 4; ++ni)
          Yout[ob + ni * 16] = (bf16_t)(acc[mi][ni][rg] + wt * bv[ni]);
      }
  } else {
    float bv[4];
    int colbase = bx * BN + wn * 64 + (lane & 15);
#pragma unroll
    for (int ni = 0; ni < 4; ++ni) bv[ni] = bias1[boff + colbase + ni * 16];
    float* Fout = (float*)Outp;
#pragma unroll
    for (int mi = 0; mi < MI; ++mi)
#pragma unroll
      for (int rg = 0; rg < 4; ++rg) {
        int Rb = ((mi >= 4) ? 128 : 0) + wm * 64 + (mi & 3) * 16;
        int rt = Rb + ((lane >> 4) << 2) + rg;
        int grow = rowstart + rt;
        size_t ob = (size_t)grow * ldOut + colbase;
#pragma unroll
        for (int ni = 0; ni < 4; ++ni)
          Fout[ob + ni * 16] = acc[mi][ni][rg] + bv[ni];
      }
  }
#undef PHASE
#undef PH128
#undef STG_A
#undef STG_B
}

// ---------------- host ----------------
extern "C" void kernel_launch(void* const* d_in, const int* in_sizes, int n_in,
                              void* d_out, int out_size, void* d_ws, size_t ws_size,
                              hipStream_t stream) {
  const float* x   = (const float*)d_in[0];
  const float* gw  = (const float*)d_in[1];
  const float* ew1 = (const float*)d_in[2];
  const float* eb1 = (const float*)d_in[3];
  const float* ew2 = (const float*)d_in[4];
  const float* eb2 = (const float*)d_in[5];
  const float* ew3 = (const float*)d_in[6];
  const float* eb3 = (const float*)d_in[7];
  const float* sw1 = (const float*)d_in[8];
  const float* sb1 = (const float*)d_in[9];
  const float* sw2 = (const float*)d_in[10];
  const float* sb2 = (const float*)d_in[11];
  const float* sw3 = (const float*)d_in[12];
  const float* sb3 = (const float*)d_in[13];
  float* out = (float*)d_out;
  (void)ws_size;

  char* ws = (char*)d_ws;
  size_t off = 0;
  auto alloc = [&](size_t bytes) -> void* {
    off = (off + 255) & ~(size_t)255;
    void* p = ws + off;
    off += bytes;
    return p;
  };

  bf16_t* xb    = (bf16_t*)alloc((size_t)TOK * DIMD * 2);                  // 16 MB
  bf16_t* ew13i = (bf16_t*)alloc((size_t)NEXP * 2 * INTERD * DIMD * 2);    // 64 MB
  bf16_t* ew2b  = (bf16_t*)alloc((size_t)NEXP * DIMD * INTERD * 2);        // 32 MB
  bf16_t* sw13i = (bf16_t*)alloc((size_t)2 * SINTER * DIMD * 2);           // 8 MB
  bf16_t* sw2b  = (bf16_t*)alloc((size_t)DIMD * SINTER * 2);               // 4 MB
  // H union: shared Hs (8192x2048) / routed Hg (36864x1024), disjoint time windows
  bf16_t* Hun   = (bf16_t*)alloc((size_t)CAP256 * INTERD * 2);             // 72 MB
  bf16_t* Hs    = Hun;
  bf16_t* Hg    = Hun;
  // Yg (72 MB bf16) ALIASES xb+ew13i (80 MB): both dead once routed gemm1 completes;
  // cvt refills them at the start of every (replayed) call.
  bf16_t* Yg    = xb;
  int*   toklist = (int*)alloc(CAP256 * 4);
  float* wtlist  = (float*)alloc(CAP256 * 4);
  int*   blkhist = (int*)alloc(HBLK * NEXP * 4);
  int*   blkbase = (int*)alloc(HBLK * NEXP * 4);
  int*   tile_e  = (int*)alloc(512 * 4);
  int*   tile_rs = (int*)alloc(512 * 4);
  int*   tkidx   = (int*)alloc((size_t)TOK * 4 * 4);
  float* tkwt    = (float*)alloc((size_t)TOK * 4 * 4);
  int4*  pos4    = (int4*)alloc((size_t)TOK * 16);

  // cvt3 also initializes toklist/wtlist/tile tables (grid covers CAP256 threads)
  cvt3_kernel<<<2048, 256, 0, stream>>>(x, xb, TOK * DIMD / 4,
                                        ew2, ew2b, NEXP * DIMD * INTERD / 4,
                                        sw2, sw2b, DIMD * SINTER / 4,
                                        toklist, wtlist, tile_e, tile_rs);
  cvt_ileave<<<2048, 256, 0, stream>>>(ew1, ew3, ew13i, NEXP * 2 * INTERD * DIMD / 4, 11);
  cvt_ileave<<<1024, 256, 0, stream>>>(sw1, sw3, sw13i, 2 * SINTER * DIMD / 4, 12);

  gate_kernel<<<TOK / 4, 256, 0, stream>>>(x, gw, tkidx, tkwt);
  hist_kernel<<<HBLK, 256, 0, stream>>>(tkidx, blkhist);
  offs_kernel<<<1, 512, 0, stream>>>(blkhist, blkbase, tile_e, tile_rs);
  scat_kernel<<<HBLK, 256, 0, stream>>>(tkidx, tkwt, blkbase, toklist, wtlist, pos4);

  // shared expert: Hs = silu(x sw1^T + sb1)*(x sw3^T + sb3); out = Hs sw2^T + sb2
  gemm8p<256, false, 0><<<dim3(2 * SINTER / 256, TOK / 256), 512, 0, stream>>>(
      xb, sw13i, sb1, sb3, Hs, nullptr, nullptr, nullptr, nullptr,
      DIMD, SINTER, 0, 0);
  gemm8p<128, false, 2><<<dim3(DIMD / 256, TOK / 128), 512, 0, stream>>>(
      Hs, sw2b, sb2, nullptr, out, nullptr, nullptr, nullptr, nullptr,
      SINTER, DIMD, 0, 0);

  // routed experts: Hg = wt * silu(.)*(.); Yg = Hg ew2^T + wt*b2 (plain bf16 store)
  gemm8p<256, true, 0><<<dim3(2 * INTERD / 256, MAXT), 512, 0, stream>>>(
      xb, ew13i, eb1, eb3, Hg, tile_e, tile_rs, toklist, wtlist,
      DIMD, INTERD, (size_t)2 * INTERD * DIMD, INTERD);
  gemm8p<256, true, 1><<<dim3(DIMD / 256, MAXT), 512, 0, stream>>>(
      Hg, ew2b, eb2, nullptr, Yg, tile_e, tile_rs, toklist, wtlist,
      INTERD, DIMD, (size_t)DIMD * INTERD, DIMD);

  // combine: out[t] += sum_k Yg[pos(t,k)]
  fuse_kernel<<<TOK, 256, 0, stream>>>(pos4, Yg, out);
}